// Round 8
// baseline (490.515 us; speedup 1.0000x reference)
//
#include <hip/hip_runtime.h>
#include <cstdint>
#include <cstddef>

namespace {

constexpr int Bb  = 8;
constexpr int Tt  = 1024;
constexpr int Dd  = 768;
constexpr int Hh  = 12;
constexpr int DFF = 3072;
constexpr int BT  = Bb * Tt;

typedef __attribute__((ext_vector_type(8))) short bf16x8;
typedef __attribute__((ext_vector_type(4))) short bf16x4;
typedef __attribute__((ext_vector_type(4))) float f32x4;

__device__ __forceinline__ short f2bf(float f) {
  union { float f; unsigned u; } v; v.f = f;
  unsigned r = v.u + 0x7fffu + ((v.u >> 16) & 1u);   // RNE
  return (short)(r >> 16);
}
__device__ __forceinline__ float gelu_exact(float v) {
  return 0.5f * v * (1.0f + erff(v * 0.70710678118654752f));
}

#define MFMA16(a, b, c) __builtin_amdgcn_mfma_f32_16x16x32_bf16(a, b, c, 0, 0, 0)
#define WAITV(n) asm volatile("s_waitcnt vmcnt(" #n ")" ::: "memory")
#define BARRIER() asm volatile("s_barrier" ::: "memory")

// async global->LDS, 16B per lane. LDS dest is wave-uniform base + lane*16.
__device__ __forceinline__ void gl_lds16(const short* g, short* l) {
  __builtin_amdgcn_global_load_lds(
      (const __attribute__((address_space(1))) unsigned int*)(g),
      (__attribute__((address_space(3))) unsigned int*)(l), 16, 0, 0);
}

// ---------- weight convert + transpose: out[n*K + k] = bf16(in[k*N + n]) ----------
__global__ __launch_bounds__(256) void cvt_t(const float* __restrict__ in,
                                             short* __restrict__ out,
                                             int K, int N) {
  __shared__ float tile[32][33];
  int k0 = blockIdx.x * 32, n0 = blockIdx.y * 32;
  int tx = threadIdx.x & 31, ty = threadIdx.x >> 5;
  #pragma unroll
  for (int r = ty; r < 32; r += 8)
    tile[r][tx] = in[(size_t)(k0 + r) * N + n0 + tx];
  __syncthreads();
  #pragma unroll
  for (int r = ty; r < 32; r += 8)
    out[(size_t)(n0 + r) * K + k0 + tx] = f2bf(tile[tx][r]);
}

// ---------- LayerNorm rows of 768: f32 in -> bf16 out (one wave per row) ----------
__global__ __launch_bounds__(256) void ln_rows(const float* __restrict__ x,
                                               const float* __restrict__ g,
                                               const float* __restrict__ b,
                                               short* __restrict__ out) {
  int lane = threadIdx.x & 63, wid = threadIdx.x >> 6;
  int row = blockIdx.x * 4 + wid;
  const float* xr = x + (size_t)row * Dd;
  float v[12];
  float s = 0.f, ss = 0.f;
  #pragma unroll
  for (int c = 0; c < 3; c++) {
    float4 t = *(const float4*)&xr[c * 256 + lane * 4];
    v[c * 4 + 0] = t.x; v[c * 4 + 1] = t.y; v[c * 4 + 2] = t.z; v[c * 4 + 3] = t.w;
    s  += t.x + t.y + t.z + t.w;
    ss += t.x * t.x + t.y * t.y + t.z * t.z + t.w * t.w;
  }
  #pragma unroll
  for (int off = 1; off < 64; off <<= 1) {
    s += __shfl_xor(s, off); ss += __shfl_xor(ss, off);
  }
  float mu   = s * (1.f / Dd);
  float var  = ss * (1.f / Dd) - mu * mu;
  float rstd = rsqrtf(var + 1e-5f);
  #pragma unroll
  for (int c = 0; c < 3; c++) {
    bf16x4 o;
    #pragma unroll
    for (int j = 0; j < 4; j++) {
      int d = c * 256 + lane * 4 + j;
      o[j] = f2bf((v[c * 4 + j] - mu) * rstd * g[d] + b[d]);
    }
    *(bf16x4*)&out[(size_t)row * Dd + c * 256 + lane * 4] = o;
  }
}

// ---------- 256x256 8-wave GEMM (QKV / fc1): C = A * Bt^T + bias ----------
// BK=64 double-buffered (128 KB LDS). Per K-tile: stage next (8 gl_lds/wave),
// vmcnt(8) BEFORE the barrier (own staging of the consumed tile is then done;
// all waves do -> tile fully visible after barrier; next-tile loads stay in
// flight). 64 MFMA between barrier pairs. XOR bank swizzle: stage slot
// c^(r&7) via inverse-swizzled global source, reads use same XOR (G21).
template <int EPI>
__global__ __launch_bounds__(512, 2) void gemm256(const short* __restrict__ A,
                                                  const short* __restrict__ Bt,
                                                  const float* __restrict__ bias,
                                                  short* __restrict__ outp,
                                                  int N, int K) {
  // buffers: [2][4 halves][8192 shorts]; halves: A0,A1,B0,B1 (128 rows x 64 k)
  __shared__ short S[65536];   // 128 KB
  int nbx = gridDim.x;
  int flat = blockIdx.y * nbx + blockIdx.x;
  int cpx = (nbx * gridDim.y) >> 3;
  int swz = (flat & 7) * cpx + (flat >> 3);
  int m0 = (swz % nbx) * 256, n0 = (swz / nbx) * 256;

  int tid = threadIdx.x;
  int lane = tid & 63, wid = tid >> 6;
  int wm = wid >> 2, wn = wid & 3;          // 2 x 4 waves; per-wave 128x64 out
  int l15 = lane & 15, lg = lane >> 4;

  // staging geometry: one gl_lds covers 8 rows (8 slots x 16B each)
  int srow = wid * 8 + (lane >> 3);          // 0..63 (half covers 128 rows via +64)
  int gslot = (lane & 7) ^ (srow & 7);       // inverse swizzle on global source

  auto stage = [&](int dbuf, int kt) {
    int dst = dbuf * 32768 + (wid << 9);
    #pragma unroll
    for (int p = 0; p < 4; ++p) {
      const short* g = (p < 2)
        ? &A [(size_t)(m0 + (p & 1) * 128 + srow) * K + kt * 64 + gslot * 8]
        : &Bt[(size_t)(n0 + (p & 1) * 128 + srow) * K + kt * 64 + gslot * 8];
      gl_lds16(g, &S[dst + p * 8192]);
      gl_lds16(g + (size_t)64 * K, &S[dst + p * 8192 + 4096]);
    }
  };

  f32x4 acc[8][4] = {};
  stage(0, 0);                               // prologue: tile 0 -> buf 0
  int NT = K >> 6;
  for (int kt = 0; kt < NT; ++kt) {
    int d = kt & 1;
    if (kt + 1 < NT) {
      stage(d ^ 1, kt + 1);                  // 8 loads for next tile
      WAITV(8);                              // own loads of CURRENT tile done
    } else {
      WAITV(0);
    }
    BARRIER();                               // now tile d fully visible (all waves)

    const int bB = d * 32768 + 16384 + (wn >> 1) * 8192;
    bf16x8 rB[8];
    #pragma unroll
    for (int n = 0; n < 4; n++) {
      int r = (wn & 1) * 64 + n * 16 + l15;
      rB[n * 2 + 0] = *(const bf16x8*)&S[bB + r * 64 + (((lg    ) ^ (r & 7)) << 3)];
      rB[n * 2 + 1] = *(const bf16x8*)&S[bB + r * 64 + (((4 + lg) ^ (r & 7)) << 3)];
    }
    const int bA = d * 32768 + wm * 8192;
    #pragma unroll
    for (int m = 0; m < 8; m++) {
      int r = m * 16 + l15;
      bf16x8 a0 = *(const bf16x8*)&S[bA + r * 64 + (((lg    ) ^ (r & 7)) << 3)];
      bf16x8 a1 = *(const bf16x8*)&S[bA + r * 64 + (((4 + lg) ^ (r & 7)) << 3)];
      #pragma unroll
      for (int n = 0; n < 4; n++) {
        acc[m][n] = MFMA16(a0, rB[n * 2 + 0], acc[m][n]);
        acc[m][n] = MFMA16(a1, rB[n * 2 + 1], acc[m][n]);
      }
    }
    BARRIER();                               // all reads of tile d done before restage
  }

  // epilogue: C through LDS (swizzled), coalesced bf16x8 stores, 128 rows/chunk
  __syncthreads();
  #pragma unroll
  for (int ch = 0; ch < 2; ++ch) {
    if (wm == ch) {
      #pragma unroll
      for (int m = 0; m < 8; m++)
        #pragma unroll
        for (int n = 0; n < 4; n++) {
          int col = wn * 64 + n * 16 + l15;
          float bs = bias[n0 + col];
          #pragma unroll
          for (int r = 0; r < 4; r++) {
            int row = m * 16 + lg * 4 + r;
            float vv = acc[m][n][r] + bs;
            if (EPI == 2) vv = gelu_exact(vv);
            S[row * 256 + ((((col >> 3) ^ (row & 7)) << 3) | (col & 7))] = f2bf(vv);
          }
        }
    }
    __syncthreads();
    int row = tid >> 2;
    #pragma unroll
    for (int c = 0; c < 8; c++) {
      int cc = (tid & 3) + c * 4;
      bf16x8 v8 = *(bf16x8*)&S[row * 256 + ((cc ^ (row & 7)) << 3)];
      *(bf16x8*)&outp[(size_t)(m0 + ch * 128 + row) * N + n0 + cc * 8] = v8;
    }
    __syncthreads();
  }
}

// ---------- 128x128 GEMM (out-proj / fc2): f32 out + residual ----------
template <int EPI, int N>
__global__ __launch_bounds__(256) void gemm_bt(const short* __restrict__ A,
                                               const short* __restrict__ Bt,
                                               const float* __restrict__ bias,
                                               const float* __restrict__ add,
                                               void* __restrict__ outp,
                                               int K) {
  __shared__ short S[17408];
  short* As0 = S;
  short* As1 = S + 4096;
  short* Bs0 = S + 8192;
  short* Bs1 = S + 12288;

  int nbx = gridDim.x;
  int flat = blockIdx.y * nbx + blockIdx.x;
  int cpx = (nbx * gridDim.y) >> 3;
  int swz = (flat & 7) * cpx + (flat >> 3);
  int m0 = (swz % nbx) * 128, n0 = (swz / nbx) * 128;

  int tid = threadIdx.x;
  int lane = tid & 63, wid = tid >> 6;
  int wm = wid >> 1, wn = wid & 1;
  int l15 = lane & 15, lg = lane >> 4;

  int jr = tid >> 2, jc = (tid & 3) << 3;
  int ldsb = wid << 9;

  auto stage = [&](short* Ad, short* Bd, int k0) {
    gl_lds16(&A[(size_t)(m0 + jr) * K + k0 + jc],       Ad + ldsb);
    gl_lds16(&A[(size_t)(m0 + 64 + jr) * K + k0 + jc],  Ad + 2048 + ldsb);
    gl_lds16(&Bt[(size_t)(n0 + jr) * K + k0 + jc],      Bd + ldsb);
    gl_lds16(&Bt[(size_t)(n0 + 64 + jr) * K + k0 + jc], Bd + 2048 + ldsb);
  };

  f32x4 acc[4][4] = {};
  stage(As0, Bs0, 0);
  int nk = K >> 5;
  for (int t = 0; t < nk; ++t) {
    short* Ab = (t & 1) ? As1 : As0;
    short* Bb = (t & 1) ? Bs1 : Bs0;
    if (t + 1 < nk) {
      stage((t & 1) ? As0 : As1, (t & 1) ? Bs0 : Bs1, (t + 1) << 5);
      asm volatile("s_waitcnt vmcnt(4)" ::: "memory");
    } else {
      asm volatile("s_waitcnt vmcnt(0)" ::: "memory");
    }
    __syncthreads();
    bf16x8 af[4], bfr[4];
    #pragma unroll
    for (int i = 0; i < 4; i++) af[i]  = *(bf16x8*)&Ab[(wm * 64 + i * 16 + l15) * 32 + lg * 8];
    #pragma unroll
    for (int j = 0; j < 4; j++) bfr[j] = *(bf16x8*)&Bb[(wn * 64 + j * 16 + l15) * 32 + lg * 8];
    #pragma unroll
    for (int i = 0; i < 4; i++)
      #pragma unroll
      for (int j = 0; j < 4; j++)
        acc[i][j] = MFMA16(af[i], bfr[j], acc[i][j]);
    __syncthreads();
  }

  #pragma unroll
  for (int i = 0; i < 4; i++)
    #pragma unroll
    for (int j = 0; j < 4; j++)
      #pragma unroll
      for (int r = 0; r < 4; r++) {
        int m = m0 + wm * 64 + i * 16 + lg * 4 + r;
        int n = n0 + wn * 64 + j * 16 + l15;
        float vv = acc[i][j][r] + bias[n];
        size_t idx = (size_t)m * N + n;
        float ov = vv + add[idx];
        if (EPI == 3) __builtin_nontemporal_store(ov, &((float*)outp)[idx]);
        else          ((float*)outp)[idx] = ov;
      }
}

// ---------- fused causal attention (unchanged from R5) ----------
__global__ __launch_bounds__(256) void attn_fused(const short* __restrict__ qkv,
                                                  float* __restrict__ attw,
                                                  short* __restrict__ ctx) {
  __shared__ short Vt[64][72];
  __shared__ float Pf[4][16][68];
  int flat = blockIdx.y * 16 + blockIdx.x;
  int xcd = flat & 7, rr0 = flat >> 3;
  int bh   = xcd * 12 + (rr0 >> 4);
  int tile = 15 - (rr0 & 15);
  int q0 = tile * 64;
  int b = bh / Hh, h = bh % Hh;
  int tid = threadIdx.x, lane = tid & 63, wid = tid >> 6;
  int l15 = lane & 15, lg = lane >> 4;
  const short* base = qkv + (size_t)b * Tt * 2304;

  bf16x8 qa[2];
  {
    const short* qp = base + (size_t)(q0 + wid * 16 + l15) * 2304 + h * 64 + lg * 8;
    qa[0] = *(const bf16x8*)qp;
    qa[1] = *(const bf16x8*)(qp + 32);
  }

  float l[4] = {0.f, 0.f, 0.f, 0.f};
  for (int kt = 0; kt <= tile; ++kt) {
    f32x4 acc[4] = {};
    #pragma unroll
    for (int nf = 0; nf < 4; ++nf) {
      const short* kp = base + (size_t)(kt * 64 + nf * 16 + l15) * 2304 + 768 + h * 64 + lg * 8;
      bf16x8 k0 = *(const bf16x8*)kp;
      bf16x8 k1 = *(const bf16x8*)(kp + 32);
      acc[nf] = MFMA16(qa[0], k0, acc[nf]);
      acc[nf] = MFMA16(qa[1], k1, acc[nf]);
    }
    #pragma unroll
    for (int r = 0; r < 4; r++) {
      int qg = q0 + wid * 16 + lg * 4 + r;
      #pragma unroll
      for (int nf = 0; nf < 4; nf++) {
        int kg = kt * 64 + nf * 16 + l15;
        l[r] += (kg <= qg) ? __expf(acc[nf][r] * 0.125f) : 0.f;
      }
    }
  }
  float rl[4];
  #pragma unroll
  for (int r = 0; r < 4; r++) {
    float s = l[r];
    #pragma unroll
    for (int off = 1; off < 16; off <<= 1) s += __shfl_xor(s, off);
    rl[r] = 1.f / s;
  }

  f32x4 oacc[4] = {};
  for (int kt = 0; kt <= tile; ++kt) {
    __syncthreads();
    {
      int t = tid & 63, dv = (tid >> 6) * 16;
      const short* vp = base + (size_t)(kt * 64 + t) * 2304 + 1536 + h * 64 + dv;
      bf16x8 v0 = *(const bf16x8*)vp;
      bf16x8 v1 = *(const bf16x8*)(vp + 8);
      #pragma unroll
      for (int j = 0; j < 8; j++) Vt[dv + j][t] = v0[j];
      #pragma unroll
      for (int j = 0; j < 8; j++) Vt[dv + 8 + j][t] = v1[j];
    }
    __syncthreads();

    f32x4 acc[4] = {};
    #pragma unroll
    for (int nf = 0; nf < 4; nf++) {
      const short* kp = base + (size_t)(kt * 64 + nf * 16 + l15) * 2304 + 768 + h * 64 + lg * 8;
      bf16x8 k0 = *(const bf16x8*)kp;
      bf16x8 k1 = *(const bf16x8*)(kp + 32);
      acc[nf] = MFMA16(qa[0], k0, acc[nf]);
      acc[nf] = MFMA16(qa[1], k1, acc[nf]);
    }
    #pragma unroll
    for (int nf = 0; nf < 4; nf++) {
      #pragma unroll
      for (int r = 0; r < 4; r++) {
        int qg = q0 + wid * 16 + lg * 4 + r;
        int kg = kt * 64 + nf * 16 + l15;
        float p = (kg <= qg) ? __expf(acc[nf][r] * 0.125f) * rl[r] : 0.f;
        Pf[wid][lg * 4 + r][nf * 16 + l15] = p;
      }
    }
    asm volatile("s_waitcnt lgkmcnt(0)" ::: "memory");
    __builtin_amdgcn_sched_barrier(0);
    #pragma unroll
    for (int it = 0; it < 4; ++it) {
      int pr = it * 4 + lg;
      f32x4 pv = *(f32x4*)&Pf[wid][pr][l15 * 4];
      __builtin_nontemporal_store(
          pv, (f32x4*)&attw[((size_t)bh * Tt + q0 + wid * 16 + pr) * Tt + kt * 64 + l15 * 4]);
    }
    f32x4 pf0 = *(f32x4*)&Pf[wid][l15][lg * 8];
    f32x4 pf1 = *(f32x4*)&Pf[wid][l15][lg * 8 + 4];
    f32x4 pf2 = *(f32x4*)&Pf[wid][l15][lg * 8 + 32];
    f32x4 pf3 = *(f32x4*)&Pf[wid][l15][lg * 8 + 36];
    bf16x8 pa0, pa1;
    #pragma unroll
    for (int j = 0; j < 4; j++) {
      pa0[j] = f2bf(pf0[j]); pa0[4 + j] = f2bf(pf1[j]);
      pa1[j] = f2bf(pf2[j]); pa1[4 + j] = f2bf(pf3[j]);
    }
    #pragma unroll
    for (int nf = 0; nf < 4; nf++) {
      bf16x8 vb0 = *(bf16x8*)&Vt[nf * 16 + l15][lg * 8];
      bf16x8 vb1 = *(bf16x8*)&Vt[nf * 16 + l15][lg * 8 + 32];
      oacc[nf] = MFMA16(pa0, vb0, oacc[nf]);
      oacc[nf] = MFMA16(pa1, vb1, oacc[nf]);
    }
  }
  f32x4 z = {0.f, 0.f, 0.f, 0.f};
  for (int kt = tile + 1; kt < 16; ++kt) {
    #pragma unroll
    for (int it = 0; it < 4; ++it) {
      int pr = it * 4 + lg;
      __builtin_nontemporal_store(
          z, (f32x4*)&attw[((size_t)bh * Tt + q0 + wid * 16 + pr) * Tt + kt * 64 + l15 * 4]);
    }
  }
  #pragma unroll
  for (int nf = 0; nf < 4; nf++) {
    #pragma unroll
    for (int r = 0; r < 4; r++) {
      int t = q0 + wid * 16 + lg * 4 + r;
      ctx[((size_t)b * Tt + t) * Dd + h * 64 + nf * 16 + l15] = f2bf(oacc[nf][r]);
    }
  }
}

}  // namespace

extern "C" void kernel_launch(void* const* d_in, const int* in_sizes, int n_in,
                              void* d_out, int out_size, void* d_ws, size_t ws_size,
                              hipStream_t stream) {
  const float* x     = (const float*)d_in[0];
  const float* ln1g  = (const float*)d_in[1];
  const float* ln1b  = (const float*)d_in[2];
  const float* w_qkv = (const float*)d_in[3];
  const float* b_qkv = (const float*)d_in[4];
  const float* w_out = (const float*)d_in[5];
  const float* b_out = (const float*)d_in[6];
  const float* ln2g  = (const float*)d_in[7];
  const float* ln2b  = (const float*)d_in[8];
  const float* w_fc1 = (const float*)d_in[9];
  const float* b_fc1 = (const float*)d_in[10];
  const float* w_fc2 = (const float*)d_in[11];
  const float* b_fc2 = (const float*)d_in[12];

  char* ws = (char*)d_ws;
  size_t o = 0;
  short* wqkvT = (short*)(ws + o); o += (size_t)2304 * 768 * 2;
  short* woutT = (short*)(ws + o); o += (size_t)768 * 768 * 2;
  short* wfc1T = (short*)(ws + o); o += (size_t)3072 * 768 * 2;
  short* wfc2T = (short*)(ws + o); o += (size_t)768 * 3072 * 2;
  short* h     = (short*)(ws + o); o += (size_t)BT * Dd * 2;
  short* qkv   = (short*)(ws + o); o += (size_t)BT * 2304 * 2;
  float* y1    = (float*)(ws + o); o += (size_t)BT * Dd * 4;
  short* h2    = (short*)(ws + o); o += (size_t)BT * Dd * 2;
  short* ctx  = h;     // reuse: h dead after QKV GEMM
  short* gbuf = h;     // reuse: h+qkv regions for GELU output (BT*DFF*2 bytes)

  float* out_x = (float*)d_out;
  float* attw  = out_x + (size_t)BT * Dd;

  cvt_t<<<dim3(768 / 32, 2304 / 32), 256, 0, stream>>>(w_qkv, wqkvT, 768, 2304);
  cvt_t<<<dim3(768 / 32, 768 / 32),  256, 0, stream>>>(w_out, woutT, 768, 768);
  cvt_t<<<dim3(768 / 32, 3072 / 32), 256, 0, stream>>>(w_fc1, wfc1T, 768, 3072);
  cvt_t<<<dim3(3072 / 32, 768 / 32), 256, 0, stream>>>(w_fc2, wfc2T, 3072, 768);

  ln_rows<<<BT / 4, 256, 0, stream>>>(x, ln1g, ln1b, h);
  gemm256<0><<<dim3(BT / 256, 2304 / 256), 512, 0, stream>>>(h, wqkvT, b_qkv, qkv, 2304, 768);
  attn_fused<<<dim3(16, 96), 256, 0, stream>>>(qkv, attw, ctx);
  gemm_bt<1, 768><<<dim3(BT / 128, 768 / 128), 256, 0, stream>>>(ctx, woutT, b_out, x, y1, 768);
  ln_rows<<<BT / 4, 256, 0, stream>>>(y1, ln2g, ln2b, h2);
  gemm256<2><<<dim3(BT / 256, DFF / 256), 512, 0, stream>>>(h2, wfc1T, b_fc1, gbuf, DFF, 768);
  gemm_bt<3, 768><<<dim3(BT / 128, 768 / 128), 256, 0, stream>>>(gbuf, wfc2T, b_fc2, y1, out_x, 3072);
}

// Round 9
// 480.417 us; speedup vs baseline: 1.0210x; 1.0210x over previous
//
#include <hip/hip_runtime.h>
#include <cstdint>
#include <cstddef>

namespace {

constexpr int Bb  = 8;
constexpr int Tt  = 1024;
constexpr int Dd  = 768;
constexpr int Hh  = 12;
constexpr int DFF = 3072;
constexpr int BT  = Bb * Tt;

typedef __attribute__((ext_vector_type(8))) short bf16x8;
typedef __attribute__((ext_vector_type(4))) short bf16x4;
typedef __attribute__((ext_vector_type(4))) float f32x4;

__device__ __forceinline__ short f2bf(float f) {
  union { float f; unsigned u; } v; v.f = f;
  unsigned r = v.u + 0x7fffu + ((v.u >> 16) & 1u);   // RNE
  return (short)(r >> 16);
}
__device__ __forceinline__ float gelu_exact(float v) {
  return 0.5f * v * (1.0f + erff(v * 0.70710678118654752f));
}

#define MFMA16(a, b, c) __builtin_amdgcn_mfma_f32_16x16x32_bf16(a, b, c, 0, 0, 0)

// async global->LDS, 16B per lane. LDS dest is wave-uniform base + lane*16.
__device__ __forceinline__ void gl_lds16(const short* g, short* l) {
  __builtin_amdgcn_global_load_lds(
      (const __attribute__((address_space(1))) unsigned int*)(g),
      (__attribute__((address_space(3))) unsigned int*)(l), 16, 0, 0);
}

// ---------- weight convert + transpose: out[n*K + k] = bf16(in[k*N + n]) ----------
__global__ __launch_bounds__(256) void cvt_t(const float* __restrict__ in,
                                             short* __restrict__ out,
                                             int K, int N) {
  __shared__ float tile[32][33];
  int k0 = blockIdx.x * 32, n0 = blockIdx.y * 32;
  int tx = threadIdx.x & 31, ty = threadIdx.x >> 5;
  #pragma unroll
  for (int r = ty; r < 32; r += 8)
    tile[r][tx] = in[(size_t)(k0 + r) * N + n0 + tx];
  __syncthreads();
  #pragma unroll
  for (int r = ty; r < 32; r += 8)
    out[(size_t)(n0 + r) * K + k0 + tx] = f2bf(tile[tx][r]);
}

// ---------- LayerNorm rows of 768: f32 in -> bf16 out (one wave per row) ----------
__global__ __launch_bounds__(256) void ln_rows(const float* __restrict__ x,
                                               const float* __restrict__ g,
                                               const float* __restrict__ b,
                                               short* __restrict__ out) {
  int lane = threadIdx.x & 63, wid = threadIdx.x >> 6;
  int row = blockIdx.x * 4 + wid;
  const float* xr = x + (size_t)row * Dd;
  float v[12];
  float s = 0.f, ss = 0.f;
  #pragma unroll
  for (int c = 0; c < 3; c++) {
    float4 t = *(const float4*)&xr[c * 256 + lane * 4];
    v[c * 4 + 0] = t.x; v[c * 4 + 1] = t.y; v[c * 4 + 2] = t.z; v[c * 4 + 3] = t.w;
    s  += t.x + t.y + t.z + t.w;
    ss += t.x * t.x + t.y * t.y + t.z * t.z + t.w * t.w;
  }
  #pragma unroll
  for (int off = 1; off < 64; off <<= 1) {
    s += __shfl_xor(s, off); ss += __shfl_xor(ss, off);
  }
  float mu   = s * (1.f / Dd);
  float var  = ss * (1.f / Dd) - mu * mu;
  float rstd = rsqrtf(var + 1e-5f);
  #pragma unroll
  for (int c = 0; c < 3; c++) {
    bf16x4 o;
    #pragma unroll
    for (int j = 0; j < 4; j++) {
      int d = c * 256 + lane * 4 + j;
      o[j] = f2bf((v[c * 4 + j] - mu) * rstd * g[d] + b[d]);
    }
    *(bf16x4*)&out[(size_t)row * Dd + c * 256 + lane * 4] = o;
  }
}

// ---------- 128x128 GEMM: C = A * Bt^T + bias (R5-proven) ----------
// EPI 0: bf16 +bias; EPI 1: f32 +bias+add; EPI 2: bf16 gelu; EPI 3: f32 nt +add
template <int EPI, int N>
__global__ __launch_bounds__(256) void gemm_bt(const short* __restrict__ A,
                                               const short* __restrict__ Bt,
                                               const float* __restrict__ bias,
                                               const float* __restrict__ add,
                                               void* __restrict__ outp,
                                               int K) {
  __shared__ short S[17408];
  short* As0 = S;
  short* As1 = S + 4096;
  short* Bs0 = S + 8192;
  short* Bs1 = S + 12288;

  int nbx = gridDim.x;
  int flat = blockIdx.y * nbx + blockIdx.x;
  int cpx = (nbx * gridDim.y) >> 3;
  int swz = (flat & 7) * cpx + (flat >> 3);
  int m0 = (swz % nbx) * 128, n0 = (swz / nbx) * 128;

  int tid = threadIdx.x;
  int lane = tid & 63, wid = tid >> 6;
  int wm = wid >> 1, wn = wid & 1;
  int l15 = lane & 15, lg = lane >> 4;

  int jr = tid >> 2, jc = (tid & 3) << 3;
  int ldsb = wid << 9;

  auto stage = [&](short* Ad, short* Bd, int k0) {
    gl_lds16(&A[(size_t)(m0 + jr) * K + k0 + jc],       Ad + ldsb);
    gl_lds16(&A[(size_t)(m0 + 64 + jr) * K + k0 + jc],  Ad + 2048 + ldsb);
    gl_lds16(&Bt[(size_t)(n0 + jr) * K + k0 + jc],      Bd + ldsb);
    gl_lds16(&Bt[(size_t)(n0 + 64 + jr) * K + k0 + jc], Bd + 2048 + ldsb);
  };

  f32x4 acc[4][4] = {};
  stage(As0, Bs0, 0);
  int nk = K >> 5;
  for (int t = 0; t < nk; ++t) {
    short* Ab = (t & 1) ? As1 : As0;
    short* Bb = (t & 1) ? Bs1 : Bs0;
    if (t + 1 < nk) {
      stage((t & 1) ? As0 : As1, (t & 1) ? Bs0 : Bs1, (t + 1) << 5);
      asm volatile("s_waitcnt vmcnt(4)" ::: "memory");
    } else {
      asm volatile("s_waitcnt vmcnt(0)" ::: "memory");
    }
    __syncthreads();
    bf16x8 af[4], bfr[4];
    #pragma unroll
    for (int i = 0; i < 4; i++) af[i]  = *(bf16x8*)&Ab[(wm * 64 + i * 16 + l15) * 32 + lg * 8];
    #pragma unroll
    for (int j = 0; j < 4; j++) bfr[j] = *(bf16x8*)&Bb[(wn * 64 + j * 16 + l15) * 32 + lg * 8];
    #pragma unroll
    for (int i = 0; i < 4; i++)
      #pragma unroll
      for (int j = 0; j < 4; j++)
        acc[i][j] = MFMA16(af[i], bfr[j], acc[i][j]);
    __syncthreads();
  }

  if (EPI == 0 || EPI == 2) {
    short (*Cl)[136] = (short (*)[136])S;
    #pragma unroll
    for (int i = 0; i < 4; i++)
      #pragma unroll
      for (int j = 0; j < 4; j++)
        #pragma unroll
        for (int r = 0; r < 4; r++) {
          int row = wm * 64 + i * 16 + lg * 4 + r;
          int col = wn * 64 + j * 16 + l15;
          float vv = acc[i][j][r] + bias[n0 + col];
          if (EPI == 2) vv = gelu_exact(vv);
          int ch = col >> 3, co = col & 7;
          Cl[row][((ch ^ (row & 7)) << 3) | co] = f2bf(vv);
        }
    __syncthreads();
    int row = tid >> 1;
    int cb = (tid & 1) * 8;
    #pragma unroll
    for (int c = 0; c < 8; c++) {
      int ch = cb + c;
      bf16x8 v8 = *(bf16x8*)&Cl[row][(ch ^ (row & 7)) << 3];
      *(bf16x8*)&((short*)outp)[(size_t)(m0 + row) * N + n0 + (ch << 3)] = v8;
    }
  } else {
    #pragma unroll
    for (int i = 0; i < 4; i++)
      #pragma unroll
      for (int j = 0; j < 4; j++)
        #pragma unroll
        for (int r = 0; r < 4; r++) {
          int m = m0 + wm * 64 + i * 16 + lg * 4 + r;
          int n = n0 + wn * 64 + j * 16 + l15;
          float vv = acc[i][j][r] + bias[n];
          size_t idx = (size_t)m * N + n;
          float ov = vv + add[idx];
          if (EPI == 3) __builtin_nontemporal_store(ov, &((float*)outp)[idx]);
          else          ((float*)outp)[idx] = ov;
        }
  }
}

// ---------- attention kernel A: ctx + row sums, single QK^T pass ----------
// Unnormalized accumulation: p = exp(s) (no max-sub, scores bounded);
// O_unnorm = sum p*V via Pf LDS transpose; l accumulated per-lane, reduced at
// end; O = O_unnorm / l. Writes ctx (bf16) + sums (f32). No attw stores.
__global__ __launch_bounds__(256) void attn_ctx(const short* __restrict__ qkv,
                                                float* __restrict__ sums,
                                                short* __restrict__ ctx) {
  __shared__ short Vt[64][72];
  __shared__ float Pf[4][16][68];
  int flat = blockIdx.y * 16 + blockIdx.x;
  int xcd = flat & 7, rr0 = flat >> 3;
  int bh   = xcd * 12 + (rr0 >> 4);
  int tile = 15 - (rr0 & 15);        // heavy first (LPT)
  int q0 = tile * 64;
  int b = bh / Hh, h = bh % Hh;
  int tid = threadIdx.x, lane = tid & 63, wid = tid >> 6;
  int l15 = lane & 15, lg = lane >> 4;
  const short* base = qkv + (size_t)b * Tt * 2304;

  bf16x8 qa[2];
  {
    const short* qp = base + (size_t)(q0 + wid * 16 + l15) * 2304 + h * 64 + lg * 8;
    qa[0] = *(const bf16x8*)qp;
    qa[1] = *(const bf16x8*)(qp + 32);
  }

  float l[4] = {0.f, 0.f, 0.f, 0.f};
  f32x4 oacc[4] = {};
  for (int kt = 0; kt <= tile; ++kt) {
    __syncthreads();                   // prior Vt reads complete
    {
      int t = tid & 63, dv = (tid >> 6) * 16;
      const short* vp = base + (size_t)(kt * 64 + t) * 2304 + 1536 + h * 64 + dv;
      bf16x8 v0 = *(const bf16x8*)vp;
      bf16x8 v1 = *(const bf16x8*)(vp + 8);
      #pragma unroll
      for (int j = 0; j < 8; j++) Vt[dv + j][t] = v0[j];
      #pragma unroll
      for (int j = 0; j < 8; j++) Vt[dv + 8 + j][t] = v1[j];
    }
    __syncthreads();

    f32x4 acc[4] = {};
    #pragma unroll
    for (int nf = 0; nf < 4; nf++) {
      const short* kp = base + (size_t)(kt * 64 + nf * 16 + l15) * 2304 + 768 + h * 64 + lg * 8;
      bf16x8 k0 = *(const bf16x8*)kp;
      bf16x8 k1 = *(const bf16x8*)(kp + 32);
      acc[nf] = MFMA16(qa[0], k0, acc[nf]);
      acc[nf] = MFMA16(qa[1], k1, acc[nf]);
    }
    #pragma unroll
    for (int nf = 0; nf < 4; nf++) {
      #pragma unroll
      for (int r = 0; r < 4; r++) {
        int qg = q0 + wid * 16 + lg * 4 + r;
        int kg = kt * 64 + nf * 16 + l15;
        float p = (kg <= qg) ? __expf(acc[nf][r] * 0.125f) : 0.f;   // UNNORMALIZED
        Pf[wid][lg * 4 + r][nf * 16 + l15] = p;
        l[r] += p;
      }
    }
    asm volatile("s_waitcnt lgkmcnt(0)" ::: "memory");
    __builtin_amdgcn_sched_barrier(0);
    f32x4 pf0 = *(f32x4*)&Pf[wid][l15][lg * 8];
    f32x4 pf1 = *(f32x4*)&Pf[wid][l15][lg * 8 + 4];
    f32x4 pf2 = *(f32x4*)&Pf[wid][l15][lg * 8 + 32];
    f32x4 pf3 = *(f32x4*)&Pf[wid][l15][lg * 8 + 36];
    bf16x8 pa0, pa1;
    #pragma unroll
    for (int j = 0; j < 4; j++) {
      pa0[j] = f2bf(pf0[j]); pa0[4 + j] = f2bf(pf1[j]);
      pa1[j] = f2bf(pf2[j]); pa1[4 + j] = f2bf(pf3[j]);
    }
    #pragma unroll
    for (int nf = 0; nf < 4; nf++) {
      bf16x8 vb0 = *(bf16x8*)&Vt[nf * 16 + l15][lg * 8];
      bf16x8 vb1 = *(bf16x8*)&Vt[nf * 16 + l15][lg * 8 + 32];
      oacc[nf] = MFMA16(pa0, vb0, oacc[nf]);
      oacc[nf] = MFMA16(pa1, vb1, oacc[nf]);
    }
  }
  // reduce row sums over the 16-lane l15 group (same row within each lg group)
  float rl[4];
  #pragma unroll
  for (int r = 0; r < 4; r++) {
    #pragma unroll
    for (int off = 1; off < 16; off <<= 1) l[r] += __shfl_xor(l[r], off);
    rl[r] = 1.f / l[r];
  }
  #pragma unroll
  for (int nf = 0; nf < 4; nf++) {
    #pragma unroll
    for (int r = 0; r < 4; r++) {
      int t = q0 + wid * 16 + lg * 4 + r;
      ctx[((size_t)b * Tt + t) * Dd + h * 64 + nf * 16 + l15] = f2bf(oacc[nf][r] * rl[r]);
    }
  }
  if (l15 == 0) {
    #pragma unroll
    for (int r = 0; r < 4; r++)
      sums[(size_t)bh * Tt + q0 + wid * 16 + lg * 4 + r] = l[r];
  }
}

// ---------- attention kernel B: attw writer (streaming, barrier-free) ----------
// Recompute QK^T, normalize by precomputed sums, store via per-wave Pf LDS with
// 256B-coalesced nontemporal f32x4 stores. No V, no PV, no __syncthreads.
__global__ __launch_bounds__(256) void attn_w(const short* __restrict__ qkv,
                                              const float* __restrict__ sums,
                                              float* __restrict__ attw) {
  __shared__ float Pf[4][16][68];
  int flat = blockIdx.y * 16 + blockIdx.x;
  int xcd = flat & 7, rr0 = flat >> 3;
  int bh   = xcd * 12 + (rr0 >> 4);
  int tile = 15 - (rr0 & 15);        // heavy first (LPT)
  int q0 = tile * 64;
  int b = bh / Hh, h = bh % Hh;
  int tid = threadIdx.x, lane = tid & 63, wid = tid >> 6;
  int l15 = lane & 15, lg = lane >> 4;
  const short* base = qkv + (size_t)b * Tt * 2304;

  bf16x8 qa[2];
  {
    const short* qp = base + (size_t)(q0 + wid * 16 + l15) * 2304 + h * 64 + lg * 8;
    qa[0] = *(const bf16x8*)qp;
    qa[1] = *(const bf16x8*)(qp + 32);
  }
  float rl[4];
  #pragma unroll
  for (int r = 0; r < 4; r++)
    rl[r] = 1.f / sums[(size_t)bh * Tt + q0 + wid * 16 + lg * 4 + r];

  for (int kt = 0; kt <= tile; ++kt) {
    f32x4 acc[4] = {};
    #pragma unroll
    for (int nf = 0; nf < 4; nf++) {
      const short* kp = base + (size_t)(kt * 64 + nf * 16 + l15) * 2304 + 768 + h * 64 + lg * 8;
      bf16x8 k0 = *(const bf16x8*)kp;
      bf16x8 k1 = *(const bf16x8*)(kp + 32);
      acc[nf] = MFMA16(qa[0], k0, acc[nf]);
      acc[nf] = MFMA16(qa[1], k1, acc[nf]);
    }
    #pragma unroll
    for (int nf = 0; nf < 4; nf++) {
      #pragma unroll
      for (int r = 0; r < 4; r++) {
        int qg = q0 + wid * 16 + lg * 4 + r;
        int kg = kt * 64 + nf * 16 + l15;
        Pf[wid][lg * 4 + r][nf * 16 + l15] =
            (kg <= qg) ? __expf(acc[nf][r] * 0.125f) * rl[r] : 0.f;
      }
    }
    asm volatile("s_waitcnt lgkmcnt(0)" ::: "memory");
    __builtin_amdgcn_sched_barrier(0);
    #pragma unroll
    for (int it = 0; it < 4; ++it) {
      int pr = it * 4 + lg;
      f32x4 pv = *(f32x4*)&Pf[wid][pr][l15 * 4];
      __builtin_nontemporal_store(
          pv, (f32x4*)&attw[((size_t)bh * Tt + q0 + wid * 16 + pr) * Tt + kt * 64 + l15 * 4]);
    }
  }
  f32x4 z = {0.f, 0.f, 0.f, 0.f};
  for (int kt = tile + 1; kt < 16; ++kt) {
    #pragma unroll
    for (int it = 0; it < 4; ++it) {
      int pr = it * 4 + lg;
      __builtin_nontemporal_store(
          z, (f32x4*)&attw[((size_t)bh * Tt + q0 + wid * 16 + pr) * Tt + kt * 64 + l15 * 4]);
    }
  }
}

}  // namespace

extern "C" void kernel_launch(void* const* d_in, const int* in_sizes, int n_in,
                              void* d_out, int out_size, void* d_ws, size_t ws_size,
                              hipStream_t stream) {
  const float* x     = (const float*)d_in[0];
  const float* ln1g  = (const float*)d_in[1];
  const float* ln1b  = (const float*)d_in[2];
  const float* w_qkv = (const float*)d_in[3];
  const float* b_qkv = (const float*)d_in[4];
  const float* w_out = (const float*)d_in[5];
  const float* b_out = (const float*)d_in[6];
  const float* ln2g  = (const float*)d_in[7];
  const float* ln2b  = (const float*)d_in[8];
  const float* w_fc1 = (const float*)d_in[9];
  const float* b_fc1 = (const float*)d_in[10];
  const float* w_fc2 = (const float*)d_in[11];
  const float* b_fc2 = (const float*)d_in[12];

  char* ws = (char*)d_ws;
  size_t o = 0;
  short* wqkvT = (short*)(ws + o); o += (size_t)2304 * 768 * 2;
  short* woutT = (short*)(ws + o); o += (size_t)768 * 768 * 2;
  short* wfc1T = (short*)(ws + o); o += (size_t)3072 * 768 * 2;
  short* wfc2T = (short*)(ws + o); o += (size_t)768 * 3072 * 2;
  short* h     = (short*)(ws + o); o += (size_t)BT * Dd * 2;
  short* qkv   = (short*)(ws + o); o += (size_t)BT * 2304 * 2;
  float* y1    = (float*)(ws + o); o += (size_t)BT * Dd * 4;
  short* h2    = (short*)(ws + o); o += (size_t)BT * Dd * 2;
  float* sums  = (float*)(ws + o); o += (size_t)96 * Tt * 4;   // 393 KB
  short* ctx  = h;     // reuse: h dead after QKV GEMM
  short* gbuf = h;     // reuse: h+qkv regions for GELU output (BT*DFF*2 bytes)

  float* out_x = (float*)d_out;
  float* attw  = out_x + (size_t)BT * Dd;

  cvt_t<<<dim3(768 / 32, 2304 / 32), 256, 0, stream>>>(w_qkv, wqkvT, 768, 2304);
  cvt_t<<<dim3(768 / 32, 768 / 32),  256, 0, stream>>>(w_out, woutT, 768, 768);
  cvt_t<<<dim3(768 / 32, 3072 / 32), 256, 0, stream>>>(w_fc1, wfc1T, 768, 3072);
  cvt_t<<<dim3(3072 / 32, 768 / 32), 256, 0, stream>>>(w_fc2, wfc2T, 3072, 768);

  ln_rows<<<BT / 4, 256, 0, stream>>>(x, ln1g, ln1b, h);
  gemm_bt<0, 2304><<<dim3(BT / 128, 2304 / 128), 256, 0, stream>>>(h, wqkvT, b_qkv, nullptr, qkv, 768);
  attn_ctx<<<dim3(16, 96), 256, 0, stream>>>(qkv, sums, ctx);
  attn_w<<<dim3(16, 96), 256, 0, stream>>>(qkv, sums, attw);
  gemm_bt<1, 768><<<dim3(BT / 128, 768 / 128), 256, 0, stream>>>(ctx, woutT, b_out, x, y1, 768);
  ln_rows<<<BT / 4, 256, 0, stream>>>(y1, ln2g, ln2b, h2);
  gemm_bt<2, 3072><<<dim3(BT / 128, 3072 / 128), 256, 0, stream>>>(h2, wfc1T, b_fc1, nullptr, gbuf, 768);
  gemm_bt<3, 768><<<dim3(BT / 128, 768 / 128), 256, 0, stream>>>(gbuf, wfc2T, b_fc2, y1, out_x, 3072);
}

// Round 11
// 471.792 us; speedup vs baseline: 1.0397x; 1.0183x over previous
//
#include <hip/hip_runtime.h>
#include <cstdint>
#include <cstddef>

namespace {

constexpr int Bb  = 8;
constexpr int Tt  = 1024;
constexpr int Dd  = 768;
constexpr int Hh  = 12;
constexpr int DFF = 3072;
constexpr int BT  = Bb * Tt;

typedef __attribute__((ext_vector_type(8))) short bf16x8;
typedef __attribute__((ext_vector_type(4))) short bf16x4;
typedef __attribute__((ext_vector_type(4))) float f32x4;

__device__ __forceinline__ short f2bf(float f) {
  union { float f; unsigned u; } v; v.f = f;
  unsigned r = v.u + 0x7fffu + ((v.u >> 16) & 1u);   // RNE
  return (short)(r >> 16);
}
__device__ __forceinline__ float gelu_exact(float v) {
  return 0.5f * v * (1.0f + erff(v * 0.70710678118654752f));
}

#define MFMA16(a, b, c) __builtin_amdgcn_mfma_f32_16x16x32_bf16(a, b, c, 0, 0, 0)

__device__ __forceinline__ void gl_lds16(const short* g, short* l) {
  __builtin_amdgcn_global_load_lds(
      (const __attribute__((address_space(1))) unsigned int*)(g),
      (__attribute__((address_space(3))) unsigned int*)(l), 16, 0, 0);
}

// ---------- weight convert + transpose ----------
__global__ __launch_bounds__(256) void cvt_t(const float* __restrict__ in,
                                             short* __restrict__ out,
                                             int K, int N) {
  __shared__ float tile[32][33];
  int k0 = blockIdx.x * 32, n0 = blockIdx.y * 32;
  int tx = threadIdx.x & 31, ty = threadIdx.x >> 5;
  #pragma unroll
  for (int r = ty; r < 32; r += 8)
    tile[r][tx] = in[(size_t)(k0 + r) * N + n0 + tx];
  __syncthreads();
  #pragma unroll
  for (int r = ty; r < 32; r += 8)
    out[(size_t)(n0 + r) * K + k0 + tx] = f2bf(tile[tx][r]);
}

// ---------- LayerNorm ----------
__global__ __launch_bounds__(256) void ln_rows(const float* __restrict__ x,
                                               const float* __restrict__ g,
                                               const float* __restrict__ b,
                                               short* __restrict__ out) {
  int lane = threadIdx.x & 63, wid = threadIdx.x >> 6;
  int row = blockIdx.x * 4 + wid;
  const float* xr = x + (size_t)row * Dd;
  float v[12];
  float s = 0.f, ss = 0.f;
  #pragma unroll
  for (int c = 0; c < 3; c++) {
    float4 t = *(const float4*)&xr[c * 256 + lane * 4];
    v[c * 4 + 0] = t.x; v[c * 4 + 1] = t.y; v[c * 4 + 2] = t.z; v[c * 4 + 3] = t.w;
    s  += t.x + t.y + t.z + t.w;
    ss += t.x * t.x + t.y * t.y + t.z * t.z + t.w * t.w;
  }
  #pragma unroll
  for (int off = 1; off < 64; off <<= 1) {
    s += __shfl_xor(s, off); ss += __shfl_xor(ss, off);
  }
  float mu   = s * (1.f / Dd);
  float var  = ss * (1.f / Dd) - mu * mu;
  float rstd = rsqrtf(var + 1e-5f);
  #pragma unroll
  for (int c = 0; c < 3; c++) {
    bf16x4 o;
    #pragma unroll
    for (int j = 0; j < 4; j++) {
      int d = c * 256 + lane * 4 + j;
      o[j] = f2bf((v[c * 4 + j] - mu) * rstd * g[d] + b[d]);
    }
    *(bf16x4*)&out[(size_t)row * Dd + c * 256 + lane * 4] = o;
  }
}

// ---------- attw writer block body (runs inside mix kernels) ----------
__device__ __forceinline__ void attw_block(short* Sraw, int job,
                                           const short* __restrict__ qkv,
                                           const float* __restrict__ sums,
                                           float* __restrict__ attw) {
  float (*Pf)[16][68] = (float (*)[16][68])Sraw;
  int bh = job >> 4;
  int tile = 15 - (job & 15);
  int q0 = tile * 64;
  int b = bh / Hh, h = bh % Hh;
  int tid = threadIdx.x, lane = tid & 63, wid = tid >> 6;
  int l15 = lane & 15, lg = lane >> 4;
  const short* base = qkv + (size_t)b * Tt * 2304;

  bf16x8 qa[2];
  {
    const short* qp = base + (size_t)(q0 + wid * 16 + l15) * 2304 + h * 64 + lg * 8;
    qa[0] = *(const bf16x8*)qp;
    qa[1] = *(const bf16x8*)(qp + 32);
  }
  float rl[4];
  #pragma unroll
  for (int r = 0; r < 4; r++)
    rl[r] = 1.f / sums[(size_t)bh * Tt + q0 + wid * 16 + lg * 4 + r];

  for (int kt = 0; kt <= tile; ++kt) {
    f32x4 acc[4] = {};
    #pragma unroll
    for (int nf = 0; nf < 4; nf++) {
      const short* kp = base + (size_t)(kt * 64 + nf * 16 + l15) * 2304 + 768 + h * 64 + lg * 8;
      bf16x8 k0 = *(const bf16x8*)kp;
      bf16x8 k1 = *(const bf16x8*)(kp + 32);
      acc[nf] = MFMA16(qa[0], k0, acc[nf]);
      acc[nf] = MFMA16(qa[1], k1, acc[nf]);
    }
    #pragma unroll
    for (int nf = 0; nf < 4; nf++) {
      #pragma unroll
      for (int r = 0; r < 4; r++) {
        int qg = q0 + wid * 16 + lg * 4 + r;
        int kg = kt * 64 + nf * 16 + l15;
        Pf[wid][lg * 4 + r][nf * 16 + l15] =
            (kg <= qg) ? __expf(acc[nf][r] * 0.125f) * rl[r] : 0.f;
      }
    }
    asm volatile("s_waitcnt lgkmcnt(0)" ::: "memory");
    __builtin_amdgcn_sched_barrier(0);
    #pragma unroll
    for (int it = 0; it < 4; ++it) {
      int pr = it * 4 + lg;
      f32x4 pv = *(f32x4*)&Pf[wid][pr][l15 * 4];
      __builtin_nontemporal_store(
          pv, (f32x4*)&attw[((size_t)bh * Tt + q0 + wid * 16 + pr) * Tt + kt * 64 + l15 * 4]);
    }
  }
  f32x4 z = {0.f, 0.f, 0.f, 0.f};
  for (int kt = tile + 1; kt < 16; ++kt) {
    #pragma unroll
    for (int it = 0; it < 4; ++it) {
      int pr = it * 4 + lg;
      __builtin_nontemporal_store(
          z, (f32x4*)&attw[((size_t)bh * Tt + q0 + wid * 16 + pr) * Tt + kt * 64 + l15 * 4]);
    }
  }
}

// ---------- 128x128 GEMM body ----------
template <int EPI, int N>
__device__ __forceinline__ void gemm_block(short* S, int g, int cpx, int nbx,
                                           const short* __restrict__ A,
                                           const short* __restrict__ Bt,
                                           const float* __restrict__ bias,
                                           const float* __restrict__ add,
                                           void* __restrict__ outp, int K) {
  short* As0 = S;
  short* As1 = S + 4096;
  short* Bs0 = S + 8192;
  short* Bs1 = S + 12288;
  int swz = (g & 7) * cpx + (g >> 3);
  int m0 = (swz % nbx) * 128, n0 = (swz / nbx) * 128;

  int tid = threadIdx.x;
  int lane = tid & 63, wid = tid >> 6;
  int wm = wid >> 1, wn = wid & 1;
  int l15 = lane & 15, lg = lane >> 4;

  int jr = tid >> 2, jc = (tid & 3) << 3;
  int ldsb = wid << 9;

  auto stage = [&](short* Ad, short* Bd, int k0) {
    gl_lds16(&A[(size_t)(m0 + jr) * K + k0 + jc],       Ad + ldsb);
    gl_lds16(&A[(size_t)(m0 + 64 + jr) * K + k0 + jc],  Ad + 2048 + ldsb);
    gl_lds16(&Bt[(size_t)(n0 + jr) * K + k0 + jc],      Bd + ldsb);
    gl_lds16(&Bt[(size_t)(n0 + 64 + jr) * K + k0 + jc], Bd + 2048 + ldsb);
  };

  f32x4 acc[4][4] = {};
  stage(As0, Bs0, 0);
  int nk = K >> 5;
  for (int t = 0; t < nk; ++t) {
    short* Ab = (t & 1) ? As1 : As0;
    short* Bb = (t & 1) ? Bs1 : Bs0;
    if (t + 1 < nk) {
      stage((t & 1) ? As0 : As1, (t & 1) ? Bs0 : Bs1, (t + 1) << 5);
      asm volatile("s_waitcnt vmcnt(4)" ::: "memory");
    } else {
      asm volatile("s_waitcnt vmcnt(0)" ::: "memory");
    }
    __syncthreads();
    bf16x8 af[4], bfr[4];
    #pragma unroll
    for (int i = 0; i < 4; i++) af[i]  = *(bf16x8*)&Ab[(wm * 64 + i * 16 + l15) * 32 + lg * 8];
    #pragma unroll
    for (int j = 0; j < 4; j++) bfr[j] = *(bf16x8*)&Bb[(wn * 64 + j * 16 + l15) * 32 + lg * 8];
    #pragma unroll
    for (int i = 0; i < 4; i++)
      #pragma unroll
      for (int j = 0; j < 4; j++)
        acc[i][j] = MFMA16(af[i], bfr[j], acc[i][j]);
    __syncthreads();
  }

  if (EPI == 0 || EPI == 2) {
    short (*Cl)[136] = (short (*)[136])S;
    #pragma unroll
    for (int i = 0; i < 4; i++)
      #pragma unroll
      for (int j = 0; j < 4; j++)
        #pragma unroll
        for (int r = 0; r < 4; r++) {
          int row = wm * 64 + i * 16 + lg * 4 + r;
          int col = wn * 64 + j * 16 + l15;
          float vv = acc[i][j][r] + bias[n0 + col];
          if (EPI == 2) vv = gelu_exact(vv);
          int ch = col >> 3, co = col & 7;
          Cl[row][((ch ^ (row & 7)) << 3) | co] = f2bf(vv);
        }
    __syncthreads();
    int row = tid >> 1;
    int cb = (tid & 1) * 8;
    #pragma unroll
    for (int c = 0; c < 8; c++) {
      int ch = cb + c;
      bf16x8 v8 = *(bf16x8*)&Cl[row][(ch ^ (row & 7)) << 3];
      *(bf16x8*)&((short*)outp)[(size_t)(m0 + row) * N + n0 + (ch << 3)] = v8;
    }
  } else {
    #pragma unroll
    for (int i = 0; i < 4; i++)
      #pragma unroll
      for (int j = 0; j < 4; j++)
        #pragma unroll
        for (int r = 0; r < 4; r++) {
          int m = m0 + wm * 64 + i * 16 + lg * 4 + r;
          int n = n0 + wn * 64 + j * 16 + l15;
          float vv = acc[i][j][r] + bias[n];
          size_t idx = (size_t)m * N + n;
          float ov = vv + add[idx];
          if (EPI == 3) __builtin_nontemporal_store(ov, &((float*)outp)[idx]);
          else          ((float*)outp)[idx] = ov;
        }
  }
}

// ---------- standalone GEMM ----------
template <int EPI, int N>
__global__ __launch_bounds__(256) void gemm_bt(const short* __restrict__ A,
                                               const short* __restrict__ Bt,
                                               const float* __restrict__ bias,
                                               const float* __restrict__ add,
                                               void* __restrict__ outp,
                                               int K) {
  __shared__ short S[17408];
  int nbx = gridDim.x;
  int flat = blockIdx.y * nbx + blockIdx.x;
  int cpx = (nbx * gridDim.y) >> 3;
  gemm_block<EPI, N>(S, flat, cpx, nbx, A, Bt, bias, add, outp, K);
}

// ---------- mixed GEMM + attw-writer kernel ----------
template <int EPI, int N, int GPG, int APG>
__global__ __launch_bounds__(256) void gemm_mix(const short* __restrict__ A,
                                                const short* __restrict__ Bt,
                                                const float* __restrict__ bias,
                                                const float* __restrict__ add,
                                                void* __restrict__ outp, int K,
                                                int nbx, int cpx,
                                                const short* __restrict__ qkv,
                                                const float* __restrict__ sums,
                                                float* __restrict__ attw,
                                                int jobBase) {
  __shared__ short S[17408];
  int bid = blockIdx.x;
  int grp = bid / (GPG + APG), r = bid % (GPG + APG);
  if (r < GPG) {
    gemm_block<EPI, N>(S, grp * GPG + r, cpx, nbx, A, Bt, bias, add, outp, K);
  } else {
    attw_block(S, jobBase + grp * APG + (r - GPG), qkv, sums, attw);
  }
}

// ---------- attention: ctx + row sums (single QK^T pass, R8-proven) ----------
__global__ __launch_bounds__(256) void attn_ctx(const short* __restrict__ qkv,
                                                float* __restrict__ sums,
                                                short* __restrict__ ctx) {
  __shared__ short Vt[64][72];
  __shared__ float Pf[4][16][68];
  int flat = blockIdx.y * 16 + blockIdx.x;
  int xcd = flat & 7, rr0 = flat >> 3;
  int bh   = xcd * 12 + (rr0 >> 4);
  int tile = 15 - (rr0 & 15);
  int q0 = tile * 64;
  int b = bh / Hh, h = bh % Hh;
  int tid = threadIdx.x, lane = tid & 63, wid = tid >> 6;
  int l15 = lane & 15, lg = lane >> 4;
  const short* base = qkv + (size_t)b * Tt * 2304;

  bf16x8 qa[2];
  {
    const short* qp = base + (size_t)(q0 + wid * 16 + l15) * 2304 + h * 64 + lg * 8;
    qa[0] = *(const bf16x8*)qp;
    qa[1] = *(const bf16x8*)(qp + 32);
  }

  float l[4] = {0.f, 0.f, 0.f, 0.f};
  f32x4 oacc[4] = {};
  for (int kt = 0; kt <= tile; ++kt) {
    __syncthreads();
    {
      int t = tid & 63, dv = (tid >> 6) * 16;
      const short* vp = base + (size_t)(kt * 64 + t) * 2304 + 1536 + h * 64 + dv;
      bf16x8 v0 = *(const bf16x8*)vp;
      bf16x8 v1 = *(const bf16x8*)(vp + 8);
      #pragma unroll
      for (int j = 0; j < 8; j++) Vt[dv + j][t] = v0[j];
      #pragma unroll
      for (int j = 0; j < 8; j++) Vt[dv + 8 + j][t] = v1[j];
    }
    __syncthreads();

    f32x4 acc[4] = {};
    #pragma unroll
    for (int nf = 0; nf < 4; nf++) {
      const short* kp = base + (size_t)(kt * 64 + nf * 16 + l15) * 2304 + 768 + h * 64 + lg * 8;
      bf16x8 k0 = *(const bf16x8*)kp;
      bf16x8 k1 = *(const bf16x8*)(kp + 32);
      acc[nf] = MFMA16(qa[0], k0, acc[nf]);
      acc[nf] = MFMA16(qa[1], k1, acc[nf]);
    }
    #pragma unroll
    for (int nf = 0; nf < 4; nf++) {
      #pragma unroll
      for (int r = 0; r < 4; r++) {
        int qg = q0 + wid * 16 + lg * 4 + r;
        int kg = kt * 64 + nf * 16 + l15;
        float p = (kg <= qg) ? __expf(acc[nf][r] * 0.125f) : 0.f;   // unnormalized
        Pf[wid][lg * 4 + r][nf * 16 + l15] = p;
        l[r] += p;
      }
    }
    asm volatile("s_waitcnt lgkmcnt(0)" ::: "memory");
    __builtin_amdgcn_sched_barrier(0);
    f32x4 pf0 = *(f32x4*)&Pf[wid][l15][lg * 8];
    f32x4 pf1 = *(f32x4*)&Pf[wid][l15][lg * 8 + 4];
    f32x4 pf2 = *(f32x4*)&Pf[wid][l15][lg * 8 + 32];
    f32x4 pf3 = *(f32x4*)&Pf[wid][l15][lg * 8 + 36];
    bf16x8 pa0, pa1;
    #pragma unroll
    for (int j = 0; j < 4; j++) {
      pa0[j] = f2bf(pf0[j]); pa0[4 + j] = f2bf(pf1[j]);
      pa1[j] = f2bf(pf2[j]); pa1[4 + j] = f2bf(pf3[j]);
    }
    #pragma unroll
    for (int nf = 0; nf < 4; nf++) {
      bf16x8 vb0 = *(bf16x8*)&Vt[nf * 16 + l15][lg * 8];
      bf16x8 vb1 = *(bf16x8*)&Vt[nf * 16 + l15][lg * 8 + 32];
      oacc[nf] = MFMA16(pa0, vb0, oacc[nf]);
      oacc[nf] = MFMA16(pa1, vb1, oacc[nf]);
    }
  }
  float rl[4];
  #pragma unroll
  for (int r = 0; r < 4; r++) {
    #pragma unroll
    for (int off = 1; off < 16; off <<= 1) l[r] += __shfl_xor(l[r], off);
    rl[r] = 1.f / l[r];
  }
  #pragma unroll
  for (int nf = 0; nf < 4; nf++) {
    #pragma unroll
    for (int r = 0; r < 4; r++) {
      int t = q0 + wid * 16 + lg * 4 + r;
      ctx[((size_t)b * Tt + t) * Dd + h * 64 + nf * 16 + l15] = f2bf(oacc[nf][r] * rl[r]);
    }
  }
  if (l15 == 0) {
    #pragma unroll
    for (int r = 0; r < 4; r++)
      sums[(size_t)bh * Tt + q0 + wid * 16 + lg * 4 + r] = l[r];
  }
}

}  // namespace

extern "C" void kernel_launch(void* const* d_in, const int* in_sizes, int n_in,
                              void* d_out, int out_size, void* d_ws, size_t ws_size,
                              hipStream_t stream) {
  const float* x     = (const float*)d_in[0];
  const float* ln1g  = (const float*)d_in[1];
  const float* ln1b  = (const float*)d_in[2];
  const float* w_qkv = (const float*)d_in[3];
  const float* b_qkv = (const float*)d_in[4];
  const float* w_out = (const float*)d_in[5];
  const float* b_out = (const float*)d_in[6];
  const float* ln2g  = (const float*)d_in[7];
  const float* ln2b  = (const float*)d_in[8];
  const float* w_fc1 = (const float*)d_in[9];
  const float* b_fc1 = (const float*)d_in[10];
  const float* w_fc2 = (const float*)d_in[11];
  const float* b_fc2 = (const float*)d_in[12];

  char* ws = (char*)d_ws;
  size_t o = 0;
  short* wqkvT = (short*)(ws + o); o += (size_t)2304 * 768 * 2;
  short* woutT = (short*)(ws + o); o += (size_t)768 * 768 * 2;
  short* wfc1T = (short*)(ws + o); o += (size_t)3072 * 768 * 2;
  short* wfc2T = (short*)(ws + o); o += (size_t)768 * 3072 * 2;
  short* h     = (short*)(ws + o); o += (size_t)BT * Dd * 2;
  short* qkv   = (short*)(ws + o); o += (size_t)BT * 2304 * 2;
  float* y1    = (float*)(ws + o); o += (size_t)BT * Dd * 4;
  short* h2    = (short*)(ws + o); o += (size_t)BT * Dd * 2;
  float* sums  = (float*)(ws + o); o += (size_t)96 * Tt * 4;
  short* ctx  = h;     // reuse: h dead after QKV GEMM

  // gbuf (BT*DFF bf16 = 50.33 MB): separate region if workspace allows —
  // REQUIRED for attw jobs in fc1/fc2 mixes (they read qkv, which the aliased
  // gbuf would clobber: R9's bug). Fallback: alias h+qkv, all attw jobs in
  // the out-proj mix (completes before fc1).
  size_t gbuf_bytes = (size_t)BT * DFF * 2;
  bool sep = (ws_size >= o + gbuf_bytes);
  short* gbuf = sep ? (short*)(ws + o) : h;

  float* out_x = (float*)d_out;
  float* attw  = out_x + (size_t)BT * Dd;

  cvt_t<<<dim3(768 / 32, 2304 / 32), 256, 0, stream>>>(w_qkv, wqkvT, 768, 2304);
  cvt_t<<<dim3(768 / 32, 768 / 32),  256, 0, stream>>>(w_out, woutT, 768, 768);
  cvt_t<<<dim3(768 / 32, 3072 / 32), 256, 0, stream>>>(w_fc1, wfc1T, 768, 3072);
  cvt_t<<<dim3(3072 / 32, 768 / 32), 256, 0, stream>>>(w_fc2, wfc2T, 3072, 768);

  ln_rows<<<BT / 4, 256, 0, stream>>>(x, ln1g, ln1b, h);
  gemm_bt<0, 2304><<<dim3(BT / 128, 2304 / 128), 256, 0, stream>>>(h, wqkvT, b_qkv, nullptr, qkv, 768);
  attn_ctx<<<dim3(16, 96), 256, 0, stream>>>(qkv, sums, ctx);

  if (sep) {
    // attw jobs spread across all three downstream GEMMs (512 each)
    gemm_mix<1, 768, 3, 4><<<896, 256, 0, stream>>>(
        ctx, woutT, b_out, x, y1, 768, 64, 384 / 8, qkv, sums, attw, 0);
    ln_rows<<<BT / 4, 256, 0, stream>>>(y1, ln2g, ln2b, h2);
    gemm_mix<2, DFF, 3, 1><<<2048, 256, 0, stream>>>(
        h2, wfc1T, b_fc1, nullptr, gbuf, 768, 64, 1536 / 8, qkv, sums, attw, 512);
    gemm_mix<3, 768, 3, 4><<<896, 256, 0, stream>>>(
        gbuf, wfc2T, b_fc2, y1, out_x, 3072, 64, 384 / 8, qkv, sums, attw, 1024);
  } else {
    // all 1536 attw jobs with out-proj (qkv still intact); fc1/fc2 standalone
    gemm_mix<1, 768, 1, 4><<<1920, 256, 0, stream>>>(
        ctx, woutT, b_out, x, y1, 768, 64, 384 / 8, qkv, sums, attw, 0);
    ln_rows<<<BT / 4, 256, 0, stream>>>(y1, ln2g, ln2b, h2);
    gemm_bt<2, DFF><<<dim3(BT / 128, DFF / 128), 256, 0, stream>>>(h2, wfc1T, b_fc1, nullptr, gbuf, 768);
    gemm_bt<3, 768><<<dim3(BT / 128, 768 / 128), 256, 0, stream>>>(gbuf, wfc2T, b_fc2, y1, out_x, 3072);
  }
}

// Round 12
// 436.757 us; speedup vs baseline: 1.1231x; 1.0802x over previous
//
#include <hip/hip_runtime.h>
#include <cstdint>
#include <cstddef>

namespace {

constexpr int Bb  = 8;
constexpr int Tt  = 1024;
constexpr int Dd  = 768;
constexpr int Hh  = 12;
constexpr int DFF = 3072;
constexpr int BT  = Bb * Tt;

typedef __attribute__((ext_vector_type(8))) short bf16x8;
typedef __attribute__((ext_vector_type(4))) short bf16x4;
typedef __attribute__((ext_vector_type(4))) float f32x4;

__device__ __forceinline__ short f2bf(float f) {
  union { float f; unsigned u; } v; v.f = f;
  unsigned r = v.u + 0x7fffu + ((v.u >> 16) & 1u);   // RNE
  return (short)(r >> 16);
}
__device__ __forceinline__ float gelu_exact(float v) {
  return 0.5f * v * (1.0f + erff(v * 0.70710678118654752f));
}

#define MFMA16(a, b, c) __builtin_amdgcn_mfma_f32_16x16x32_bf16(a, b, c, 0, 0, 0)

__device__ __forceinline__ void gl_lds16(const short* g, short* l) {
  __builtin_amdgcn_global_load_lds(
      (const __attribute__((address_space(1))) unsigned int*)(g),
      (__attribute__((address_space(3))) unsigned int*)(l), 16, 0, 0);
}

// ---------- weight convert + transpose ----------
__global__ __launch_bounds__(256) void cvt_t(const float* __restrict__ in,
                                             short* __restrict__ out,
                                             int K, int N) {
  __shared__ float tile[32][33];
  int k0 = blockIdx.x * 32, n0 = blockIdx.y * 32;
  int tx = threadIdx.x & 31, ty = threadIdx.x >> 5;
  #pragma unroll
  for (int r = ty; r < 32; r += 8)
    tile[r][tx] = in[(size_t)(k0 + r) * N + n0 + tx];
  __syncthreads();
  #pragma unroll
  for (int r = ty; r < 32; r += 8)
    out[(size_t)(n0 + r) * K + k0 + tx] = f2bf(tile[tx][r]);
}

// ---------- LayerNorm ----------
__global__ __launch_bounds__(256) void ln_rows(const float* __restrict__ x,
                                               const float* __restrict__ g,
                                               const float* __restrict__ b,
                                               short* __restrict__ out) {
  int lane = threadIdx.x & 63, wid = threadIdx.x >> 6;
  int row = blockIdx.x * 4 + wid;
  const float* xr = x + (size_t)row * Dd;
  float v[12];
  float s = 0.f, ss = 0.f;
  #pragma unroll
  for (int c = 0; c < 3; c++) {
    float4 t = *(const float4*)&xr[c * 256 + lane * 4];
    v[c * 4 + 0] = t.x; v[c * 4 + 1] = t.y; v[c * 4 + 2] = t.z; v[c * 4 + 3] = t.w;
    s  += t.x + t.y + t.z + t.w;
    ss += t.x * t.x + t.y * t.y + t.z * t.z + t.w * t.w;
  }
  #pragma unroll
  for (int off = 1; off < 64; off <<= 1) {
    s += __shfl_xor(s, off); ss += __shfl_xor(ss, off);
  }
  float mu   = s * (1.f / Dd);
  float var  = ss * (1.f / Dd) - mu * mu;
  float rstd = rsqrtf(var + 1e-5f);
  #pragma unroll
  for (int c = 0; c < 3; c++) {
    bf16x4 o;
    #pragma unroll
    for (int j = 0; j < 4; j++) {
      int d = c * 256 + lane * 4 + j;
      o[j] = f2bf((v[c * 4 + j] - mu) * rstd * g[d] + b[d]);
    }
    *(bf16x4*)&out[(size_t)row * Dd + c * 256 + lane * 4] = o;
  }
}

// ---------- V transpose: vt[bh][d][t] = V[b,t,h,d] (R4-verified) ----------
__global__ __launch_bounds__(256) void vtr(const short* __restrict__ qkv,
                                           short* __restrict__ vt) {
  __shared__ short Ts[64][72];
  int bh = blockIdx.x, t0 = blockIdx.y * 64;
  int b = bh / Hh, h = bh % Hh;
  int tid = threadIdx.x;
  int r = tid >> 2, dc = (tid & 3) * 16;
  const short* vp = qkv + (size_t)b * Tt * 2304 + (size_t)(t0 + r) * 2304 + 1536 + h * 64 + dc;
  bf16x8 v0 = *(const bf16x8*)vp;
  bf16x8 v1 = *(const bf16x8*)(vp + 8);
  *(bf16x8*)&Ts[r][dc] = v0;
  *(bf16x8*)&Ts[r][dc + 8] = v1;
  __syncthreads();
  int d = tid >> 2, tc = (tid & 3) * 16;
  bf16x8 o0, o1;
  #pragma unroll
  for (int j = 0; j < 8; j++) { o0[j] = Ts[tc + j][d]; o1[j] = Ts[tc + 8 + j][d]; }
  short* op = vt + ((size_t)bh * 64 + d) * Tt + t0 + tc;
  *(bf16x8*)op = o0;
  *(bf16x8*)(op + 8) = o1;
}

// ---------- 128x128 GEMM (R5-proven, unchanged) ----------
template <int EPI, int N>
__global__ __launch_bounds__(256) void gemm_bt(const short* __restrict__ A,
                                               const short* __restrict__ Bt,
                                               const float* __restrict__ bias,
                                               const float* __restrict__ add,
                                               void* __restrict__ outp,
                                               int K) {
  __shared__ short S[17408];
  short* As0 = S;
  short* As1 = S + 4096;
  short* Bs0 = S + 8192;
  short* Bs1 = S + 12288;

  int nbx = gridDim.x;
  int flat = blockIdx.y * nbx + blockIdx.x;
  int cpx = (nbx * gridDim.y) >> 3;
  int swz = (flat & 7) * cpx + (flat >> 3);
  int m0 = (swz % nbx) * 128, n0 = (swz / nbx) * 128;

  int tid = threadIdx.x;
  int lane = tid & 63, wid = tid >> 6;
  int wm = wid >> 1, wn = wid & 1;
  int l15 = lane & 15, lg = lane >> 4;

  int jr = tid >> 2, jc = (tid & 3) << 3;
  int ldsb = wid << 9;

  auto stage = [&](short* Ad, short* Bd, int k0) {
    gl_lds16(&A[(size_t)(m0 + jr) * K + k0 + jc],       Ad + ldsb);
    gl_lds16(&A[(size_t)(m0 + 64 + jr) * K + k0 + jc],  Ad + 2048 + ldsb);
    gl_lds16(&Bt[(size_t)(n0 + jr) * K + k0 + jc],      Bd + ldsb);
    gl_lds16(&Bt[(size_t)(n0 + 64 + jr) * K + k0 + jc], Bd + 2048 + ldsb);
  };

  f32x4 acc[4][4] = {};
  stage(As0, Bs0, 0);
  int nk = K >> 5;
  for (int t = 0; t < nk; ++t) {
    short* Ab = (t & 1) ? As1 : As0;
    short* Bb = (t & 1) ? Bs1 : Bs0;
    if (t + 1 < nk) {
      stage((t & 1) ? As0 : As1, (t & 1) ? Bs0 : Bs1, (t + 1) << 5);
      asm volatile("s_waitcnt vmcnt(4)" ::: "memory");
    } else {
      asm volatile("s_waitcnt vmcnt(0)" ::: "memory");
    }
    __syncthreads();
    bf16x8 af[4], bfr[4];
    #pragma unroll
    for (int i = 0; i < 4; i++) af[i]  = *(bf16x8*)&Ab[(wm * 64 + i * 16 + l15) * 32 + lg * 8];
    #pragma unroll
    for (int j = 0; j < 4; j++) bfr[j] = *(bf16x8*)&Bb[(wn * 64 + j * 16 + l15) * 32 + lg * 8];
    #pragma unroll
    for (int i = 0; i < 4; i++)
      #pragma unroll
      for (int j = 0; j < 4; j++)
        acc[i][j] = MFMA16(af[i], bfr[j], acc[i][j]);
    __syncthreads();
  }

  if (EPI == 0 || EPI == 2) {
    short (*Cl)[136] = (short (*)[136])S;
    #pragma unroll
    for (int i = 0; i < 4; i++)
      #pragma unroll
      for (int j = 0; j < 4; j++)
        #pragma unroll
        for (int r = 0; r < 4; r++) {
          int row = wm * 64 + i * 16 + lg * 4 + r;
          int col = wn * 64 + j * 16 + l15;
          float vv = acc[i][j][r] + bias[n0 + col];
          if (EPI == 2) vv = gelu_exact(vv);
          int ch = col >> 3, co = col & 7;
          Cl[row][((ch ^ (row & 7)) << 3) | co] = f2bf(vv);
        }
    __syncthreads();
    int row = tid >> 1;
    int cb = (tid & 1) * 8;
    #pragma unroll
    for (int c = 0; c < 8; c++) {
      int ch = cb + c;
      bf16x8 v8 = *(bf16x8*)&Cl[row][(ch ^ (row & 7)) << 3];
      *(bf16x8*)&((short*)outp)[(size_t)(m0 + row) * N + n0 + (ch << 3)] = v8;
    }
  } else {
    #pragma unroll
    for (int i = 0; i < 4; i++)
      #pragma unroll
      for (int j = 0; j < 4; j++)
        #pragma unroll
        for (int r = 0; r < 4; r++) {
          int m = m0 + wm * 64 + i * 16 + lg * 4 + r;
          int n = n0 + wn * 64 + j * 16 + l15;
          float vv = acc[i][j][r] + bias[n];
          size_t idx = (size_t)m * N + n;
          float ov = vv + add[idx];
          if (EPI == 3) __builtin_nontemporal_store(ov, &((float*)outp)[idx]);
          else          ((float*)outp)[idx] = ov;
        }
  }
}

// ---------- fused causal attention (R5 structure; async V via vt + gl_lds) ----------
// Pass 1: per-lane sumexp (no max-sub). Pass 2 per kt: QK^T (K loads imply own
// V-stage retired), exp -> Pf, nt attw stores, vmcnt(4) [stage loads retired,
// stores NOT drained] + raw s_barrier, stage V(kt+1) into other buffer, PV.
// One barrier per kt; nt stores never drained mid-loop.
__global__ __launch_bounds__(256) void attn_fused(const short* __restrict__ qkv,
                                                  const short* __restrict__ vt,
                                                  float* __restrict__ attw,
                                                  short* __restrict__ ctx) {
  __shared__ short VtL[2][4096];     // [64 d][8 chunks of 8 t] XOR-swizzled, 2x8KB
  __shared__ float Pf[4][16][68];
  int flat = blockIdx.y * 16 + blockIdx.x;
  int xcd = flat & 7, rr0 = flat >> 3;
  int bh   = xcd * 12 + (rr0 >> 4);
  int tile = 15 - (rr0 & 15);        // heavy first (LPT)
  int q0 = tile * 64;
  int b = bh / Hh, h = bh % Hh;
  int tid = threadIdx.x, lane = tid & 63, wid = tid >> 6;
  int l15 = lane & 15, lg = lane >> 4;
  const short* base = qkv + (size_t)b * Tt * 2304;

  bf16x8 qa[2];
  {
    const short* qp = base + (size_t)(q0 + wid * 16 + l15) * 2304 + h * 64 + lg * 8;
    qa[0] = *(const bf16x8*)qp;
    qa[1] = *(const bf16x8*)(qp + 32);
  }

  // ---- pass 1: per-lane sumexp only ----
  float l[4] = {0.f, 0.f, 0.f, 0.f};
  for (int kt = 0; kt <= tile; ++kt) {
    f32x4 acc[4] = {};
    #pragma unroll
    for (int nf = 0; nf < 4; ++nf) {
      const short* kp = base + (size_t)(kt * 64 + nf * 16 + l15) * 2304 + 768 + h * 64 + lg * 8;
      bf16x8 k0 = *(const bf16x8*)kp;
      bf16x8 k1 = *(const bf16x8*)(kp + 32);
      acc[nf] = MFMA16(qa[0], k0, acc[nf]);
      acc[nf] = MFMA16(qa[1], k1, acc[nf]);
    }
    #pragma unroll
    for (int r = 0; r < 4; r++) {
      int qg = q0 + wid * 16 + lg * 4 + r;
      #pragma unroll
      for (int nf = 0; nf < 4; nf++) {
        int kg = kt * 64 + nf * 16 + l15;
        l[r] += (kg <= qg) ? __expf(acc[nf][r] * 0.125f) : 0.f;
      }
    }
  }
  float rl[4];
  #pragma unroll
  for (int r = 0; r < 4; r++) {
    float s = l[r];
    #pragma unroll
    for (int off = 1; off < 16; off <<= 1) s += __shfl_xor(s, off);
    rl[r] = 1.f / s;
  }

  // ---- pass 2 ----
  const short* vtb = vt + (size_t)bh * 64 * Tt;   // [64 d][1024 t]
  int dS = wid * 16 + (lane >> 3);                // this lane's d (q=0 call)
  int cS = (lane & 7) ^ (lane >> 3);              // inverse-swizzled source chunk
  auto stageV = [&](int bi, int kt) {
    gl_lds16(&vtb[(size_t)dS * Tt + kt * 64 + cS * 8],       &VtL[bi][wid * 1024]);
    gl_lds16(&vtb[(size_t)(dS + 8) * Tt + kt * 64 + cS * 8], &VtL[bi][wid * 1024 + 512]);
  };

  f32x4 oacc[4] = {};
  stageV(0, 0);
  for (int kt = 0; kt <= tile; ++kt) {
    int cur = kt & 1;
    // QK^T (K loads are younger than V(kt) stage -> compiler's K-wait retires it)
    f32x4 acc[4] = {};
    #pragma unroll
    for (int nf = 0; nf < 4; nf++) {
      const short* kp = base + (size_t)(kt * 64 + nf * 16 + l15) * 2304 + 768 + h * 64 + lg * 8;
      bf16x8 k0 = *(const bf16x8*)kp;
      bf16x8 k1 = *(const bf16x8*)(kp + 32);
      acc[nf] = MFMA16(qa[0], k0, acc[nf]);
      acc[nf] = MFMA16(qa[1], k1, acc[nf]);
    }
    #pragma unroll
    for (int nf = 0; nf < 4; nf++) {
      #pragma unroll
      for (int r = 0; r < 4; r++) {
        int qg = q0 + wid * 16 + lg * 4 + r;
        int kg = kt * 64 + nf * 16 + l15;
        float p = (kg <= qg) ? __expf(acc[nf][r] * 0.125f) * rl[r] : 0.f;
        Pf[wid][lg * 4 + r][nf * 16 + l15] = p;
      }
    }
    asm volatile("s_waitcnt lgkmcnt(0)" ::: "memory");
    __builtin_amdgcn_sched_barrier(0);
    // coalesced nt attw stores (4 x f32x4, 256B/row segments)
    #pragma unroll
    for (int it = 0; it < 4; ++it) {
      int pr = it * 4 + lg;
      f32x4 pv = *(f32x4*)&Pf[wid][pr][l15 * 4];
      __builtin_nontemporal_store(
          pv, (f32x4*)&attw[((size_t)bh * Tt + q0 + wid * 16 + pr) * Tt + kt * 64 + l15 * 4]);
    }
    // P fragments
    f32x4 pf0 = *(f32x4*)&Pf[wid][l15][lg * 8];
    f32x4 pf1 = *(f32x4*)&Pf[wid][l15][lg * 8 + 4];
    f32x4 pf2 = *(f32x4*)&Pf[wid][l15][lg * 8 + 32];
    f32x4 pf3 = *(f32x4*)&Pf[wid][l15][lg * 8 + 36];
    bf16x8 pa0, pa1;
    #pragma unroll
    for (int j = 0; j < 4; j++) {
      pa0[j] = f2bf(pf0[j]); pa0[4 + j] = f2bf(pf1[j]);
      pa1[j] = f2bf(pf2[j]); pa1[4 + j] = f2bf(pf3[j]);
    }
    // V(kt) retired in all waves (<=4 newest outstanding = this iter's stores);
    // barrier makes it visible + confirms all waves done reading buf cur^1.
    asm volatile("s_waitcnt vmcnt(4)" ::: "memory");
    __builtin_amdgcn_s_barrier();
    __builtin_amdgcn_sched_barrier(0);
    if (kt < tile) stageV(cur ^ 1, kt + 1);   // async, stays in flight
    #pragma unroll
    for (int nf = 0; nf < 4; nf++) {
      int dA = nf * 16 + l15;
      int sw = dA & 7;
      bf16x8 vb0 = *(bf16x8*)&VtL[cur][dA * 64 + ((lg ^ sw) << 3)];
      bf16x8 vb1 = *(bf16x8*)&VtL[cur][dA * 64 + (((4 + lg) ^ sw) << 3)];
      oacc[nf] = MFMA16(pa0, vb0, oacc[nf]);
      oacc[nf] = MFMA16(pa1, vb1, oacc[nf]);
    }
  }
  // strictly-upper zero tiles
  f32x4 z = {0.f, 0.f, 0.f, 0.f};
  for (int kt = tile + 1; kt < 16; ++kt) {
    #pragma unroll
    for (int it = 0; it < 4; ++it) {
      int pr = it * 4 + lg;
      __builtin_nontemporal_store(
          z, (f32x4*)&attw[((size_t)bh * Tt + q0 + wid * 16 + pr) * Tt + kt * 64 + l15 * 4]);
    }
  }
  #pragma unroll
  for (int nf = 0; nf < 4; nf++) {
    #pragma unroll
    for (int r = 0; r < 4; r++) {
      int t = q0 + wid * 16 + lg * 4 + r;
      ctx[((size_t)b * Tt + t) * Dd + h * 64 + nf * 16 + l15] = f2bf(oacc[nf][r]);
    }
  }
}

}  // namespace

extern "C" void kernel_launch(void* const* d_in, const int* in_sizes, int n_in,
                              void* d_out, int out_size, void* d_ws, size_t ws_size,
                              hipStream_t stream) {
  const float* x     = (const float*)d_in[0];
  const float* ln1g  = (const float*)d_in[1];
  const float* ln1b  = (const float*)d_in[2];
  const float* w_qkv = (const float*)d_in[3];
  const float* b_qkv = (const float*)d_in[4];
  const float* w_out = (const float*)d_in[5];
  const float* b_out = (const float*)d_in[6];
  const float* ln2g  = (const float*)d_in[7];
  const float* ln2b  = (const float*)d_in[8];
  const float* w_fc1 = (const float*)d_in[9];
  const float* b_fc1 = (const float*)d_in[10];
  const float* w_fc2 = (const float*)d_in[11];
  const float* b_fc2 = (const float*)d_in[12];

  char* ws = (char*)d_ws;
  size_t o = 0;
  short* wqkvT = (short*)(ws + o); o += (size_t)2304 * 768 * 2;
  short* woutT = (short*)(ws + o); o += (size_t)768 * 768 * 2;
  short* wfc1T = (short*)(ws + o); o += (size_t)3072 * 768 * 2;
  short* wfc2T = (short*)(ws + o); o += (size_t)768 * 3072 * 2;
  short* h     = (short*)(ws + o); o += (size_t)BT * Dd * 2;
  short* qkv   = (short*)(ws + o); o += (size_t)BT * 2304 * 2;
  float* y1    = (float*)(ws + o); o += (size_t)BT * Dd * 4;
  short* h2    = (short*)(ws + o); o += (size_t)BT * Dd * 2;
  short* vt    = (short*)(ws + o); o += (size_t)96 * 64 * Tt * 2;   // 12.58 MB (R4-proven size)
  short* ctx  = h;     // reuse: h dead after QKV GEMM
  short* gbuf = h;     // reuse: h+qkv for GELU output (attw fully written before fc1)

  float* out_x = (float*)d_out;
  float* attw  = out_x + (size_t)BT * Dd;

  cvt_t<<<dim3(768 / 32, 2304 / 32), 256, 0, stream>>>(w_qkv, wqkvT, 768, 2304);
  cvt_t<<<dim3(768 / 32, 768 / 32),  256, 0, stream>>>(w_out, woutT, 768, 768);
  cvt_t<<<dim3(768 / 32, 3072 / 32), 256, 0, stream>>>(w_fc1, wfc1T, 768, 3072);
  cvt_t<<<dim3(3072 / 32, 768 / 32), 256, 0, stream>>>(w_fc2, wfc2T, 3072, 768);

  ln_rows<<<BT / 4, 256, 0, stream>>>(x, ln1g, ln1b, h);
  gemm_bt<0, 2304><<<dim3(BT / 128, 2304 / 128), 256, 0, stream>>>(h, wqkvT, b_qkv, nullptr, qkv, 768);
  vtr<<<dim3(96, 16), 256, 0, stream>>>(qkv, vt);
  attn_fused<<<dim3(16, 96), 256, 0, stream>>>(qkv, vt, attw, ctx);
  gemm_bt<1, 768><<<dim3(BT / 128, 768 / 128), 256, 0, stream>>>(ctx, woutT, b_out, x, y1, 768);
  ln_rows<<<BT / 4, 256, 0, stream>>>(y1, ln2g, ln2b, h2);
  gemm_bt<2, 3072><<<dim3(BT / 128, 3072 / 128), 256, 0, stream>>>(h2, wfc1T, b_fc1, nullptr, gbuf, 768);
  gemm_bt<3, 768><<<dim3(BT / 128, 768 / 128), 256, 0, stream>>>(gbuf, wfc2T, b_fc2, y1, out_x, 3072);
}

// Round 13
// 432.857 us; speedup vs baseline: 1.1332x; 1.0090x over previous
//
#include <hip/hip_runtime.h>
#include <cstdint>
#include <cstddef>

namespace {

constexpr int Bb  = 8;
constexpr int Tt  = 1024;
constexpr int Dd  = 768;
constexpr int Hh  = 12;
constexpr int DFF = 3072;
constexpr int BT  = Bb * Tt;

typedef __attribute__((ext_vector_type(8))) short bf16x8;
typedef __attribute__((ext_vector_type(4))) short bf16x4;
typedef __attribute__((ext_vector_type(4))) float f32x4;

__device__ __forceinline__ short f2bf(float f) {
  union { float f; unsigned u; } v; v.f = f;
  unsigned r = v.u + 0x7fffu + ((v.u >> 16) & 1u);   // RNE
  return (short)(r >> 16);
}
__device__ __forceinline__ float gelu_exact(float v) {
  return 0.5f * v * (1.0f + erff(v * 0.70710678118654752f));
}

#define MFMA16(a, b, c) __builtin_amdgcn_mfma_f32_16x16x32_bf16(a, b, c, 0, 0, 0)

__device__ __forceinline__ void gl_lds16(const short* g, short* l) {
  __builtin_amdgcn_global_load_lds(
      (const __attribute__((address_space(1))) unsigned int*)(g),
      (__attribute__((address_space(3))) unsigned int*)(l), 16, 0, 0);
}

// ---------- weight convert + transpose ----------
__global__ __launch_bounds__(256) void cvt_t(const float* __restrict__ in,
                                             short* __restrict__ out,
                                             int K, int N) {
  __shared__ float tile[32][33];
  int k0 = blockIdx.x * 32, n0 = blockIdx.y * 32;
  int tx = threadIdx.x & 31, ty = threadIdx.x >> 5;
  #pragma unroll
  for (int r = ty; r < 32; r += 8)
    tile[r][tx] = in[(size_t)(k0 + r) * N + n0 + tx];
  __syncthreads();
  #pragma unroll
  for (int r = ty; r < 32; r += 8)
    out[(size_t)(n0 + r) * K + k0 + tx] = f2bf(tile[tx][r]);
}

// ---------- LayerNorm ----------
__global__ __launch_bounds__(256) void ln_rows(const float* __restrict__ x,
                                               const float* __restrict__ g,
                                               const float* __restrict__ b,
                                               short* __restrict__ out) {
  int lane = threadIdx.x & 63, wid = threadIdx.x >> 6;
  int row = blockIdx.x * 4 + wid;
  const float* xr = x + (size_t)row * Dd;
  float v[12];
  float s = 0.f, ss = 0.f;
  #pragma unroll
  for (int c = 0; c < 3; c++) {
    float4 t = *(const float4*)&xr[c * 256 + lane * 4];
    v[c * 4 + 0] = t.x; v[c * 4 + 1] = t.y; v[c * 4 + 2] = t.z; v[c * 4 + 3] = t.w;
    s  += t.x + t.y + t.z + t.w;
    ss += t.x * t.x + t.y * t.y + t.z * t.z + t.w * t.w;
  }
  #pragma unroll
  for (int off = 1; off < 64; off <<= 1) {
    s += __shfl_xor(s, off); ss += __shfl_xor(ss, off);
  }
  float mu   = s * (1.f / Dd);
  float var  = ss * (1.f / Dd) - mu * mu;
  float rstd = rsqrtf(var + 1e-5f);
  #pragma unroll
  for (int c = 0; c < 3; c++) {
    bf16x4 o;
    #pragma unroll
    for (int j = 0; j < 4; j++) {
      int d = c * 256 + lane * 4 + j;
      o[j] = f2bf((v[c * 4 + j] - mu) * rstd * g[d] + b[d]);
    }
    *(bf16x4*)&out[(size_t)row * Dd + c * 256 + lane * 4] = o;
  }
}

// ---------- V transpose: vt[bh][d][t] = V[b,t,h,d] ----------
__global__ __launch_bounds__(256) void vtr(const short* __restrict__ qkv,
                                           short* __restrict__ vt) {
  __shared__ short Ts[64][72];
  int bh = blockIdx.x, t0 = blockIdx.y * 64;
  int b = bh / Hh, h = bh % Hh;
  int tid = threadIdx.x;
  int r = tid >> 2, dc = (tid & 3) * 16;
  const short* vp = qkv + (size_t)b * Tt * 2304 + (size_t)(t0 + r) * 2304 + 1536 + h * 64 + dc;
  bf16x8 v0 = *(const bf16x8*)vp;
  bf16x8 v1 = *(const bf16x8*)(vp + 8);
  *(bf16x8*)&Ts[r][dc] = v0;
  *(bf16x8*)&Ts[r][dc + 8] = v1;
  __syncthreads();
  int d = tid >> 2, tc = (tid & 3) * 16;
  bf16x8 o0, o1;
  #pragma unroll
  for (int j = 0; j < 8; j++) { o0[j] = Ts[tc + j][d]; o1[j] = Ts[tc + 8 + j][d]; }
  short* op = vt + ((size_t)bh * 64 + d) * Tt + t0 + tc;
  *(bf16x8*)op = o0;
  *(bf16x8*)(op + 8) = o1;
}

// ---------- 128x128 GEMM (QKV / fc1, bf16 epilogues; R5-proven) ----------
template <int EPI, int N>
__global__ __launch_bounds__(256) void gemm_bt(const short* __restrict__ A,
                                               const short* __restrict__ Bt,
                                               const float* __restrict__ bias,
                                               const float* __restrict__ add,
                                               void* __restrict__ outp,
                                               int K) {
  __shared__ short S[17408];
  short* As0 = S;
  short* As1 = S + 4096;
  short* Bs0 = S + 8192;
  short* Bs1 = S + 12288;

  int nbx = gridDim.x;
  int flat = blockIdx.y * nbx + blockIdx.x;
  int cpx = (nbx * gridDim.y) >> 3;
  int swz = (flat & 7) * cpx + (flat >> 3);
  int m0 = (swz % nbx) * 128, n0 = (swz / nbx) * 128;

  int tid = threadIdx.x;
  int lane = tid & 63, wid = tid >> 6;
  int wm = wid >> 1, wn = wid & 1;
  int l15 = lane & 15, lg = lane >> 4;

  int jr = tid >> 2, jc = (tid & 3) << 3;
  int ldsb = wid << 9;

  auto stage = [&](short* Ad, short* Bd, int k0) {
    gl_lds16(&A[(size_t)(m0 + jr) * K + k0 + jc],       Ad + ldsb);
    gl_lds16(&A[(size_t)(m0 + 64 + jr) * K + k0 + jc],  Ad + 2048 + ldsb);
    gl_lds16(&Bt[(size_t)(n0 + jr) * K + k0 + jc],      Bd + ldsb);
    gl_lds16(&Bt[(size_t)(n0 + 64 + jr) * K + k0 + jc], Bd + 2048 + ldsb);
  };

  f32x4 acc[4][4] = {};
  stage(As0, Bs0, 0);
  int nk = K >> 5;
  for (int t = 0; t < nk; ++t) {
    short* Ab = (t & 1) ? As1 : As0;
    short* Bb = (t & 1) ? Bs1 : Bs0;
    if (t + 1 < nk) {
      stage((t & 1) ? As0 : As1, (t & 1) ? Bs0 : Bs1, (t + 1) << 5);
      asm volatile("s_waitcnt vmcnt(4)" ::: "memory");
    } else {
      asm volatile("s_waitcnt vmcnt(0)" ::: "memory");
    }
    __syncthreads();
    bf16x8 af[4], bfr[4];
    #pragma unroll
    for (int i = 0; i < 4; i++) af[i]  = *(bf16x8*)&Ab[(wm * 64 + i * 16 + l15) * 32 + lg * 8];
    #pragma unroll
    for (int j = 0; j < 4; j++) bfr[j] = *(bf16x8*)&Bb[(wn * 64 + j * 16 + l15) * 32 + lg * 8];
    #pragma unroll
    for (int i = 0; i < 4; i++)
      #pragma unroll
      for (int j = 0; j < 4; j++)
        acc[i][j] = MFMA16(af[i], bfr[j], acc[i][j]);
    __syncthreads();
  }

  if (EPI == 0 || EPI == 2) {
    short (*Cl)[136] = (short (*)[136])S;
    #pragma unroll
    for (int i = 0; i < 4; i++)
      #pragma unroll
      for (int j = 0; j < 4; j++)
        #pragma unroll
        for (int r = 0; r < 4; r++) {
          int row = wm * 64 + i * 16 + lg * 4 + r;
          int col = wn * 64 + j * 16 + l15;
          float vv = acc[i][j][r] + bias[n0 + col];
          if (EPI == 2) vv = gelu_exact(vv);
          int ch = col >> 3, co = col & 7;
          Cl[row][((ch ^ (row & 7)) << 3) | co] = f2bf(vv);
        }
    __syncthreads();
    int row = tid >> 1;
    int cb = (tid & 1) * 8;
    #pragma unroll
    for (int c = 0; c < 8; c++) {
      int ch = cb + c;
      bf16x8 v8 = *(bf16x8*)&Cl[row][(ch ^ (row & 7)) << 3];
      *(bf16x8*)&((short*)outp)[(size_t)(m0 + row) * N + n0 + (ch << 3)] = v8;
    }
  } else {
    #pragma unroll
    for (int i = 0; i < 4; i++)
      #pragma unroll
      for (int j = 0; j < 4; j++)
        #pragma unroll
        for (int r = 0; r < 4; r++) {
          int m = m0 + wm * 64 + i * 16 + lg * 4 + r;
          int n = n0 + wn * 64 + j * 16 + l15;
          float vv = acc[i][j][r] + bias[n];
          size_t idx = (size_t)m * N + n;
          float ov = vv + add[idx];
          if (EPI == 3) __builtin_nontemporal_store(ov, &((float*)outp)[idx]);
          else          ((float*)outp)[idx] = ov;
        }
  }
}

// ---------- 64x128 GEMM for N=768 outputs (out-proj / fc2): f32 + residual ----------
// Grid (M/64=128, 6) = 768 blocks (vs 384 at 128² -> 3/CU co-resident, no
// half-empty machine). Same 2-phase schedule, 3 gl_lds/stage, vmcnt(3).
template <int EPI>
__global__ __launch_bounds__(256) void gemm_n64(const short* __restrict__ A,
                                                const short* __restrict__ Bt,
                                                const float* __restrict__ bias,
                                                const float* __restrict__ add,
                                                float* __restrict__ outp,
                                                int K) {
  constexpr int N = 768;
  __shared__ short S[12288];          // 24.6 KB
  short* As0 = S;                     // 64x32
  short* As1 = S + 2048;
  short* Bs0 = S + 4096;              // 128x32
  short* Bs1 = S + 8192;

  int nbx = gridDim.x;                // 128
  int flat = blockIdx.y * nbx + blockIdx.x;
  int cpx = (nbx * gridDim.y) >> 3;
  int swz = (flat & 7) * cpx + (flat >> 3);
  int m0 = (swz % nbx) * 64, n0 = (swz / nbx) * 128;

  int tid = threadIdx.x;
  int lane = tid & 63, wid = tid >> 6;
  int wm = wid & 1, wn = wid >> 1;    // wave: rows wm*32..+32, cols wn*64..+64... (wn 0..1)
  int l15 = lane & 15, lg = lane >> 4;

  int jr = tid >> 2, jc = (tid & 3) << 3;
  int ldsb = wid << 9;

  auto stage = [&](short* Ad, short* Bd, int k0) {
    gl_lds16(&A[(size_t)(m0 + jr) * K + k0 + jc],       Ad + ldsb);
    gl_lds16(&Bt[(size_t)(n0 + jr) * K + k0 + jc],      Bd + ldsb);
    gl_lds16(&Bt[(size_t)(n0 + 64 + jr) * K + k0 + jc], Bd + 2048 + ldsb);
  };

  f32x4 acc[2][4] = {};
  stage(As0, Bs0, 0);
  int nk = K >> 5;
  for (int t = 0; t < nk; ++t) {
    short* Ab = (t & 1) ? As1 : As0;
    short* Bb = (t & 1) ? Bs1 : Bs0;
    if (t + 1 < nk) {
      stage((t & 1) ? As0 : As1, (t & 1) ? Bs0 : Bs1, (t + 1) << 5);
      asm volatile("s_waitcnt vmcnt(3)" ::: "memory");
    } else {
      asm volatile("s_waitcnt vmcnt(0)" ::: "memory");
    }
    __syncthreads();
    bf16x8 af[2], bfr[4];
    #pragma unroll
    for (int i = 0; i < 2; i++) af[i]  = *(bf16x8*)&Ab[(wm * 32 + i * 16 + l15) * 32 + lg * 8];
    #pragma unroll
    for (int j = 0; j < 4; j++) bfr[j] = *(bf16x8*)&Bb[(wn * 64 + j * 16 + l15) * 32 + lg * 8];
    #pragma unroll
    for (int i = 0; i < 2; i++)
      #pragma unroll
      for (int j = 0; j < 4; j++)
        acc[i][j] = MFMA16(af[i], bfr[j], acc[i][j]);
    __syncthreads();
  }

  #pragma unroll
  for (int i = 0; i < 2; i++)
    #pragma unroll
    for (int j = 0; j < 4; j++)
      #pragma unroll
      for (int r = 0; r < 4; r++) {
        int m = m0 + wm * 32 + i * 16 + lg * 4 + r;
        int n = n0 + wn * 64 + j * 16 + l15;
        float vv = acc[i][j][r] + bias[n];
        size_t idx = (size_t)m * N + n;
        float ov = vv + add[idx];
        if (EPI == 3) __builtin_nontemporal_store(ov, &outp[idx]);
        else          outp[idx] = ov;
      }
}

// ---------- fused causal attention (R11-proven, unchanged) ----------
__global__ __launch_bounds__(256) void attn_fused(const short* __restrict__ qkv,
                                                  const short* __restrict__ vt,
                                                  float* __restrict__ attw,
                                                  short* __restrict__ ctx) {
  __shared__ short VtL[2][4096];
  __shared__ float Pf[4][16][68];
  int flat = blockIdx.y * 16 + blockIdx.x;
  int xcd = flat & 7, rr0 = flat >> 3;
  int bh   = xcd * 12 + (rr0 >> 4);
  int tile = 15 - (rr0 & 15);
  int q0 = tile * 64;
  int b = bh / Hh, h = bh % Hh;
  int tid = threadIdx.x, lane = tid & 63, wid = tid >> 6;
  int l15 = lane & 15, lg = lane >> 4;
  const short* base = qkv + (size_t)b * Tt * 2304;

  bf16x8 qa[2];
  {
    const short* qp = base + (size_t)(q0 + wid * 16 + l15) * 2304 + h * 64 + lg * 8;
    qa[0] = *(const bf16x8*)qp;
    qa[1] = *(const bf16x8*)(qp + 32);
  }

  float l[4] = {0.f, 0.f, 0.f, 0.f};
  for (int kt = 0; kt <= tile; ++kt) {
    f32x4 acc[4] = {};
    #pragma unroll
    for (int nf = 0; nf < 4; ++nf) {
      const short* kp = base + (size_t)(kt * 64 + nf * 16 + l15) * 2304 + 768 + h * 64 + lg * 8;
      bf16x8 k0 = *(const bf16x8*)kp;
      bf16x8 k1 = *(const bf16x8*)(kp + 32);
      acc[nf] = MFMA16(qa[0], k0, acc[nf]);
      acc[nf] = MFMA16(qa[1], k1, acc[nf]);
    }
    #pragma unroll
    for (int r = 0; r < 4; r++) {
      int qg = q0 + wid * 16 + lg * 4 + r;
      #pragma unroll
      for (int nf = 0; nf < 4; nf++) {
        int kg = kt * 64 + nf * 16 + l15;
        l[r] += (kg <= qg) ? __expf(acc[nf][r] * 0.125f) : 0.f;
      }
    }
  }
  float rl[4];
  #pragma unroll
  for (int r = 0; r < 4; r++) {
    float s = l[r];
    #pragma unroll
    for (int off = 1; off < 16; off <<= 1) s += __shfl_xor(s, off);
    rl[r] = 1.f / s;
  }

  const short* vtb = vt + (size_t)bh * 64 * Tt;
  int dS = wid * 16 + (lane >> 3);
  int cS = (lane & 7) ^ (lane >> 3);
  auto stageV = [&](int bi, int kt) {
    gl_lds16(&vtb[(size_t)dS * Tt + kt * 64 + cS * 8],       &VtL[bi][wid * 1024]);
    gl_lds16(&vtb[(size_t)(dS + 8) * Tt + kt * 64 + cS * 8], &VtL[bi][wid * 1024 + 512]);
  };

  f32x4 oacc[4] = {};
  stageV(0, 0);
  for (int kt = 0; kt <= tile; ++kt) {
    int cur = kt & 1;
    f32x4 acc[4] = {};
    #pragma unroll
    for (int nf = 0; nf < 4; nf++) {
      const short* kp = base + (size_t)(kt * 64 + nf * 16 + l15) * 2304 + 768 + h * 64 + lg * 8;
      bf16x8 k0 = *(const bf16x8*)kp;
      bf16x8 k1 = *(const bf16x8*)(kp + 32);
      acc[nf] = MFMA16(qa[0], k0, acc[nf]);
      acc[nf] = MFMA16(qa[1], k1, acc[nf]);
    }
    #pragma unroll
    for (int nf = 0; nf < 4; nf++) {
      #pragma unroll
      for (int r = 0; r < 4; r++) {
        int qg = q0 + wid * 16 + lg * 4 + r;
        int kg = kt * 64 + nf * 16 + l15;
        float p = (kg <= qg) ? __expf(acc[nf][r] * 0.125f) * rl[r] : 0.f;
        Pf[wid][lg * 4 + r][nf * 16 + l15] = p;
      }
    }
    asm volatile("s_waitcnt lgkmcnt(0)" ::: "memory");
    __builtin_amdgcn_sched_barrier(0);
    #pragma unroll
    for (int it = 0; it < 4; ++it) {
      int pr = it * 4 + lg;
      f32x4 pv = *(f32x4*)&Pf[wid][pr][l15 * 4];
      __builtin_nontemporal_store(
          pv, (f32x4*)&attw[((size_t)bh * Tt + q0 + wid * 16 + pr) * Tt + kt * 64 + l15 * 4]);
    }
    f32x4 pf0 = *(f32x4*)&Pf[wid][l15][lg * 8];
    f32x4 pf1 = *(f32x4*)&Pf[wid][l15][lg * 8 + 4];
    f32x4 pf2 = *(f32x4*)&Pf[wid][l15][lg * 8 + 32];
    f32x4 pf3 = *(f32x4*)&Pf[wid][l15][lg * 8 + 36];
    bf16x8 pa0, pa1;
    #pragma unroll
    for (int j = 0; j < 4; j++) {
      pa0[j] = f2bf(pf0[j]); pa0[4 + j] = f2bf(pf1[j]);
      pa1[j] = f2bf(pf2[j]); pa1[4 + j] = f2bf(pf3[j]);
    }
    asm volatile("s_waitcnt vmcnt(4)" ::: "memory");
    __builtin_amdgcn_s_barrier();
    __builtin_amdgcn_sched_barrier(0);
    if (kt < tile) stageV(cur ^ 1, kt + 1);
    #pragma unroll
    for (int nf = 0; nf < 4; nf++) {
      int dA = nf * 16 + l15;
      int sw = dA & 7;
      bf16x8 vb0 = *(bf16x8*)&VtL[cur][dA * 64 + ((lg ^ sw) << 3)];
      bf16x8 vb1 = *(bf16x8*)&VtL[cur][dA * 64 + (((4 + lg) ^ sw) << 3)];
      oacc[nf] = MFMA16(pa0, vb0, oacc[nf]);
      oacc[nf] = MFMA16(pa1, vb1, oacc[nf]);
    }
  }
  f32x4 z = {0.f, 0.f, 0.f, 0.f};
  for (int kt = tile + 1; kt < 16; ++kt) {
    #pragma unroll
    for (int it = 0; it < 4; ++it) {
      int pr = it * 4 + lg;
      __builtin_nontemporal_store(
          z, (f32x4*)&attw[((size_t)bh * Tt + q0 + wid * 16 + pr) * Tt + kt * 64 + l15 * 4]);
    }
  }
  #pragma unroll
  for (int nf = 0; nf < 4; nf++) {
    #pragma unroll
    for (int r = 0; r < 4; r++) {
      int t = q0 + wid * 16 + lg * 4 + r;
      ctx[((size_t)b * Tt + t) * Dd + h * 64 + nf * 16 + l15] = f2bf(oacc[nf][r]);
    }
  }
}

}  // namespace

extern "C" void kernel_launch(void* const* d_in, const int* in_sizes, int n_in,
                              void* d_out, int out_size, void* d_ws, size_t ws_size,
                              hipStream_t stream) {
  const float* x     = (const float*)d_in[0];
  const float* ln1g  = (const float*)d_in[1];
  const float* ln1b  = (const float*)d_in[2];
  const float* w_qkv = (const float*)d_in[3];
  const float* b_qkv = (const float*)d_in[4];
  const float* w_out = (const float*)d_in[5];
  const float* b_out = (const float*)d_in[6];
  const float* ln2g  = (const float*)d_in[7];
  const float* ln2b  = (const float*)d_in[8];
  const float* w_fc1 = (const float*)d_in[9];
  const float* b_fc1 = (const float*)d_in[10];
  const float* w_fc2 = (const float*)d_in[11];
  const float* b_fc2 = (const float*)d_in[12];

  char* ws = (char*)d_ws;
  size_t o = 0;
  short* wqkvT = (short*)(ws + o); o += (size_t)2304 * 768 * 2;
  short* woutT = (short*)(ws + o); o += (size_t)768 * 768 * 2;
  short* wfc1T = (short*)(ws + o); o += (size_t)3072 * 768 * 2;
  short* wfc2T = (short*)(ws + o); o += (size_t)768 * 3072 * 2;
  short* h     = (short*)(ws + o); o += (size_t)BT * Dd * 2;
  short* qkv   = (short*)(ws + o); o += (size_t)BT * 2304 * 2;
  float* y1    = (float*)(ws + o); o += (size_t)BT * Dd * 4;
  short* h2    = (short*)(ws + o); o += (size_t)BT * Dd * 2;
  short* vt    = (short*)(ws + o); o += (size_t)96 * 64 * Tt * 2;
  short* ctx  = h;     // reuse: h dead after QKV GEMM
  short* gbuf = h;     // reuse: h+qkv for GELU output (attw fully written before fc1)

  float* out_x = (float*)d_out;
  float* attw  = out_x + (size_t)BT * Dd;

  cvt_t<<<dim3(768 / 32, 2304 / 32), 256, 0, stream>>>(w_qkv, wqkvT, 768, 2304);
  cvt_t<<<dim3(768 / 32, 768 / 32),  256, 0, stream>>>(w_out, woutT, 768, 768);
  cvt_t<<<dim3(768 / 32, 3072 / 32), 256, 0, stream>>>(w_fc1, wfc1T, 768, 3072);
  cvt_t<<<dim3(3072 / 32, 768 / 32), 256, 0, stream>>>(w_fc2, wfc2T, 3072, 768);

  ln_rows<<<BT / 4, 256, 0, stream>>>(x, ln1g, ln1b, h);
  gemm_bt<0, 2304><<<dim3(BT / 128, 2304 / 128), 256, 0, stream>>>(h, wqkvT, b_qkv, nullptr, qkv, 768);
  vtr<<<dim3(96, 16), 256, 0, stream>>>(qkv, vt);
  attn_fused<<<dim3(16, 96), 256, 0, stream>>>(qkv, vt, attw, ctx);
  gemm_n64<1><<<dim3(BT / 64, 768 / 128), 256, 0, stream>>>(ctx, woutT, b_out, x, y1, 768);
  ln_rows<<<BT / 4, 256, 0, stream>>>(y1, ln2g, ln2b, h2);
  gemm_bt<2, 3072><<<dim3(BT / 128, 3072 / 128), 256, 0, stream>>>(h2, wfc1T, b_fc1, nullptr, gbuf, 768);
  gemm_n64<3><<<dim3(BT / 64, 768 / 128), 256, 0, stream>>>(gbuf, wfc2T, b_fc2, y1, out_x, 3072);
}